// Round 16
// baseline (919.634 us; speedup 1.0000x reference)
//
#include <hip/hip_runtime.h>
#include <math.h>

static constexpr int NN   = 20000;
static constexpr int TT   = 6;
static constexpr int EE   = 640000;
static constexpr int CINC = 3;
static constexpr int HH   = 64;
static constexpr int RB   = 8;    // nodes per wave in the dense kernels
static constexpr int BKSH = 7;    // 128 nodes per bucket
static constexpr int NBKT = (NN + (1 << BKSH) - 1) >> BKSH;  // 157
static constexpr int CAP  = 6144; // bucket capacity (expected 4096, +32 sigma)
static constexpr int EPB  = 4096; // edges per workgroup in bin phase

// ---- bf16 helpers (storage = ushort) ------------------------------------
__device__ inline unsigned short f2bf(float f) {
    unsigned u = __float_as_uint(f);
    unsigned r = (u + 0x7FFFu + ((u >> 16) & 1u)) >> 16;  // RTNE
    return (unsigned short)r;
}
__device__ inline float bflo(unsigned u) { return __uint_as_float(u << 16); }
__device__ inline float bfhi(unsigned u) { return __uint_as_float(u & 0xFFFF0000u); }

// ---- phase 1: bin edges into 157 coarse buckets (packed dstLocal|src) ----
__global__ void bin6_kernel(const int* __restrict__ edges, int* __restrict__ gcur,
                            int* __restrict__ bucketArr) {
    int t = blockIdx.y;
    __shared__ int hist[NBKT];
    __shared__ int base[NBKT];
    int tid = threadIdx.x;
    for (int i = tid; i < NBKT; i += 256) hist[i] = 0;
    __syncthreads();
    const int* src = edges + (size_t)t * 2 * EE;
    const int* dst = src + EE;
    int e0 = blockIdx.x * EPB;
    int pack[16], loff[16], bkt[16];
    int m = 0;
#pragma unroll
    for (int i = 0; i < 16; ++i) {
        int e = e0 + tid + i * 256;
        if (e < EE) {
            int s = src[e], d = dst[e];
            int b = d >> BKSH;
            bkt[i] = b;
            pack[i] = ((d & 127) << 16) | s;
            loff[i] = atomicAdd(&hist[b], 1);
            m = i + 1;
        }
    }
    __syncthreads();
    for (int i = tid; i < NBKT; i += 256)
        base[i] = atomicAdd(&gcur[t * NBKT + i], hist[i]);
    __syncthreads();
    for (int i = 0; i < m; ++i) {
        int b = bkt[i];
        int pos = base[b] + loff[i];
        if (pos < CAP)
            bucketArr[(size_t)(t * NBKT + b) * CAP + pos] = pack[i];
    }
}

// ---- per-node degree from buckets: LDS histogram, coalesced write -------
__global__ void bucket_count6_kernel(const int* __restrict__ gcur,
                                     const int* __restrict__ bucketArr,
                                     int* __restrict__ cnt6) {
    int bk = blockIdx.x, t = blockIdx.y;
    __shared__ int hist[128];
    int tid = threadIdx.x;
    if (tid < 128) hist[tid] = 0;
    __syncthreads();
    int ecnt = gcur[t * NBKT + bk];
    if (ecnt > CAP) ecnt = CAP;
    const int* barr = bucketArr + (size_t)(t * NBKT + bk) * CAP;
    for (int e = tid; e < ecnt; e += 256) atomicAdd(&hist[barr[e] >> 16], 1);
    __syncthreads();
    int n = (bk << BKSH) + tid;
    if (tid < 128 && n < NN) cnt6[t * NN + n] = hist[tid];
}

// 6 blocks (one per t), 1024 threads: exclusive scan -> rowptr, plus dinv
__global__ void scan6_kernel(const int* __restrict__ cnt6, int* __restrict__ rowptr6,
                             float* __restrict__ dinv6) {
    int t = blockIdx.x;
    const int* cnt = cnt6 + t * NN;
    int* rowptr = rowptr6 + t * (NN + 1);
    float* dinv = dinv6 + t * NN;
    __shared__ int part[1024];
    const int CHUNK = 20;  // 1024*20 >= NN
    int tid = threadIdx.x;
    int base = tid * CHUNK;
    int local[CHUNK];
    int s = 0;
#pragma unroll
    for (int i = 0; i < CHUNK; ++i) {
        int idx = base + i;
        int v = (idx < NN) ? cnt[idx] : 0;
        local[i] = s;
        s += v;
    }
    part[tid] = s;
    __syncthreads();
    for (int off = 1; off < 1024; off <<= 1) {
        int v = part[tid];
        int add = (tid >= off) ? part[tid - off] : 0;
        __syncthreads();
        part[tid] = v + add;
        __syncthreads();
    }
    int ebase = (tid == 0) ? 0 : part[tid - 1];
#pragma unroll
    for (int i = 0; i < CHUNK; ++i) {
        int idx = base + i;
        if (idx < NN) {
            rowptr[idx] = ebase + local[i];
            dinv[idx] = rsqrtf((float)cnt[idx] + 1.0f);
        }
    }
    if (tid == 1023) rowptr[NN] = part[1023];
}

// ---- phase 2: in-LDS regroup of each bucket into per-node CSR segments ---
__global__ void regroup6_kernel(const int* __restrict__ rowptr6, const int* __restrict__ gcur,
                                const int* __restrict__ bucketArr, int* __restrict__ col6) {
    int bk = blockIdx.x, t = blockIdx.y;
    __shared__ int cursor[128];
    __shared__ int lcol[CAP];  // 24KB
    int tid = threadIdx.x;
    const int* rowptr = rowptr6 + t * (NN + 1);
    int nb0 = bk << BKSH;
    int base = rowptr[nb0];
    if (tid < 128) {
        int n = nb0 + tid;
        if (n < NN) cursor[tid] = rowptr[n] - base;
    }
    __syncthreads();
    int ecnt = gcur[t * NBKT + bk];
    if (ecnt > CAP) ecnt = CAP;
    const int* barr = bucketArr + (size_t)(t * NBKT + bk) * CAP;
    for (int e = tid; e < ecnt; e += 256) {
        int w = barr[e];
        int dl = w >> 16, s = w & 0xFFFF;
        int off = atomicAdd(&cursor[dl], 1);
        lcol[off] = s;
    }
    __syncthreads();
    int* colt = col6 + (size_t)t * EE + base;
    for (int e = tid; e < ecnt; e += 256) colt[e] = lcol[e];
}

// ---- GRU weight repack (bf16):
//   Wi[k*64+jj]  = uint2{ ir | iz<<16 , in }          (input-side, for giall)
//   Wh01[k*64+jj]= hr | hz<<16 ; Whn[k*64+jj] = hn    (hidden-side, for gru6)
__global__ void pack_gru_kernel(const float* __restrict__ wih, const float* __restrict__ whh,
                                uint2* __restrict__ Wi, unsigned* __restrict__ Wh01,
                                unsigned short* __restrict__ Whn) {
    int idx = blockIdx.x * blockDim.x + threadIdx.x;  // k*64 + jj
    if (idx >= HH * HH) return;
    int k = idx >> 6, jj = idx & 63;
    unsigned w_ir = f2bf(wih[jj * HH + k]);
    unsigned w_iz = f2bf(wih[(64 + jj) * HH + k]);
    unsigned w_in = f2bf(wih[(128 + jj) * HH + k]);
    unsigned w_hr = f2bf(whh[jj * HH + k]);
    unsigned w_hz = f2bf(whh[(64 + jj) * HH + k]);
    unsigned w_hn = f2bf(whh[(128 + jj) * HH + k]);
    Wi[idx] = make_uint2(w_ir | (w_iz << 16), w_in);
    Wh01[idx] = w_hr | (w_hz << 16);
    Whn[idx] = (unsigned short)w_hn;
}

// ---- y1 for ALL t: y = dinv * (x @ W1), bf16 out ------------------------
__global__ void y1all_kernel(const float* __restrict__ nf, const float* __restrict__ W1,
                             const float* __restrict__ dinv6, unsigned short* __restrict__ Yb) {
    int t = blockIdx.y;
    int gid = blockIdx.x * blockDim.x + threadIdx.x;
    if (gid >= NN * HH) return;
    int node = gid >> 6, hh = gid & 63;
    const float* xr = nf + (size_t)t * NN * CINC + node * CINC;
    float acc = 0.f;
#pragma unroll
    for (int k = 0; k < CINC; ++k) acc = fmaf(xr[k], W1[k * HH + hh], acc);
    Yb[(size_t)t * NN * HH + gid] = f2bf(dinv6[t * NN + node] * acc);
}

// ---- y2 for ALL t: y = dinv * (z @ W2), bf16 in/out ---------------------
__global__ void y2all_kernel(const unsigned short* __restrict__ Zb6, const float* __restrict__ W2,
                             const float* __restrict__ dinv6, unsigned short* __restrict__ Y2all) {
    int t = blockIdx.y;
    const unsigned short* z = Zb6 + (size_t)t * NN * HH;
    const float* dinv = dinv6 + t * NN;
    unsigned short* y = Y2all + (size_t)t * NN * HH;
    int nbase = blockIdx.x * RB;
    int lane = threadIdx.x;
    float acc[RB];
#pragma unroll
    for (int r = 0; r < RB; ++r) acc[r] = 0.f;
    for (int k0 = 0; k0 < 16; ++k0) {
        uint2 zv[RB];
#pragma unroll
        for (int r = 0; r < RB; ++r)
            zv[r] = *(const uint2*)(z + ((size_t)(nbase + r) << 6) + (k0 << 2));
#pragma unroll
        for (int u = 0; u < 4; ++u) {
            float w = W2[(k0 * 4 + u) * HH + lane];
#pragma unroll
            for (int r = 0; r < RB; ++r) {
                float zk = (u == 0) ? bflo(zv[r].x) : (u == 1) ? bfhi(zv[r].x)
                         : (u == 2) ? bflo(zv[r].y) : bfhi(zv[r].y);
                acc[r] = fmaf(zk, w, acc[r]);
            }
        }
    }
#pragma unroll
    for (int r = 0; r < RB; ++r)
        y[((size_t)(nbase + r) << 6) + lane] = f2bf(dinv[nbase + r] * acc[r]);
}

// ---- CSR gather for ALL t (bf16 rows -> bf16 z): z = relu(dinv*(sum+self)+b)
__global__ void gather6_kernel(const int* __restrict__ rowptr6, const int* __restrict__ col6,
                               const float* __restrict__ dinv6, const unsigned short* __restrict__ ybase,
                               const float* __restrict__ b, unsigned short* __restrict__ zbase) {
    int t = blockIdx.y;
    const int* rowptr = rowptr6 + t * (NN + 1);
    const int* col = col6 + (size_t)t * EE;
    const float* dinv = dinv6 + t * NN;
    const unsigned short* y = ybase + (size_t)t * NN * HH;
    unsigned short* z = zbase + (size_t)t * NN * HH;

    int node = (blockIdx.x * blockDim.x + threadIdx.x) >> 6;
    if (node >= NN) return;
    int lane = threadIdx.x & 63;
    int g = lane >> 3, q = lane & 7;
    int ps = rowptr[node], pe = rowptr[node + 1];
    float acc[8];
    if (g == 0) {  // self term
        const uint4 v = *(const uint4*)(y + ((size_t)node << 6) + (q << 3));
        acc[0] = bflo(v.x); acc[1] = bfhi(v.x);
        acc[2] = bflo(v.y); acc[3] = bfhi(v.y);
        acc[4] = bflo(v.z); acc[5] = bfhi(v.z);
        acc[6] = bflo(v.w); acc[7] = bfhi(v.w);
    } else {
#pragma unroll
        for (int j = 0; j < 8; ++j) acc[j] = 0.f;
    }
    for (int p = ps + g; p < pe; p += 8) {
        int c = col[p];
        const uint4 v = *(const uint4*)(y + ((size_t)c << 6) + (q << 3));
        acc[0] += bflo(v.x); acc[1] += bfhi(v.x);
        acc[2] += bflo(v.y); acc[3] += bfhi(v.y);
        acc[4] += bflo(v.z); acc[5] += bfhi(v.z);
        acc[6] += bflo(v.w); acc[7] += bfhi(v.w);
    }
#pragma unroll
    for (int j = 0; j < 8; ++j) {
        acc[j] += __shfl_xor(acc[j], 8);
        acc[j] += __shfl_xor(acc[j], 16);
        acc[j] += __shfl_xor(acc[j], 32);
    }
    if (g == 0) {
        float d = dinv[node];
        const float4 b0 = *(const float4*)(b + (q << 3));
        const float4 b1 = *(const float4*)(b + (q << 3) + 4);
        float o[8];
        o[0] = fmaf(d, acc[0], b0.x); o[1] = fmaf(d, acc[1], b0.y);
        o[2] = fmaf(d, acc[2], b0.z); o[3] = fmaf(d, acc[3], b0.w);
        o[4] = fmaf(d, acc[4], b1.x); o[5] = fmaf(d, acc[5], b1.y);
        o[6] = fmaf(d, acc[6], b1.z); o[7] = fmaf(d, acc[7], b1.w);
#pragma unroll
        for (int j = 0; j < 8; ++j) o[j] = o[j] > 0.f ? o[j] : 0.f;
        uint4 w;
        w.x = (unsigned)f2bf(o[0]) | ((unsigned)f2bf(o[1]) << 16);
        w.y = (unsigned)f2bf(o[2]) | ((unsigned)f2bf(o[3]) << 16);
        w.z = (unsigned)f2bf(o[4]) | ((unsigned)f2bf(o[5]) << 16);
        w.w = (unsigned)f2bf(o[6]) | ((unsigned)f2bf(o[7]) << 16);
        *(uint4*)(z + ((size_t)node << 6) + (q << 3)) = w;
    }
}

// ---- gi precompute for ALL t: gi[t][n][192] = z@wihT + bih (bf16) -------
// h-independent, fully parallel. One wave per RB nodes, lane = jj.
__global__ void giall_kernel(const unsigned short* __restrict__ Zb6, const uint2* __restrict__ Wi,
                             const float* __restrict__ bih, unsigned short* __restrict__ gi) {
    int t = blockIdx.y;
    const unsigned short* z = Zb6 + (size_t)t * NN * HH;
    int nbase = blockIdx.x * RB;
    int lane = threadIdx.x;
    float aR[RB], aZ[RB], aN[RB];
#pragma unroll
    for (int r = 0; r < RB; ++r) { aR[r] = aZ[r] = aN[r] = 0.f; }
    for (int k0 = 0; k0 < 16; ++k0) {
        uint2 zv[RB];
#pragma unroll
        for (int r = 0; r < RB; ++r)
            zv[r] = *(const uint2*)(z + ((size_t)(nbase + r) << 6) + (k0 << 2));
#pragma unroll
        for (int u = 0; u < 4; ++u) {
            uint2 w = Wi[((k0 * 4 + u) << 6) + lane];
            float w_ir = bflo(w.x), w_iz = bfhi(w.x), w_in = bflo(w.y);
#pragma unroll
            for (int r = 0; r < RB; ++r) {
                float zk = (u == 0) ? bflo(zv[r].x) : (u == 1) ? bfhi(zv[r].x)
                         : (u == 2) ? bflo(zv[r].y) : bfhi(zv[r].y);
                aR[r] = fmaf(zk, w_ir, aR[r]);
                aZ[r] = fmaf(zk, w_iz, aZ[r]);
                aN[r] = fmaf(zk, w_in, aN[r]);
            }
        }
    }
    float bi0 = bih[lane], bi1 = bih[64 + lane], bi2 = bih[128 + lane];
#pragma unroll
    for (int r = 0; r < RB; ++r) {
        unsigned short* gp = gi + ((size_t)t * NN + nbase + r) * 192;
        gp[lane]       = f2bf(aR[r] + bi0);
        gp[64 + lane]  = f2bf(aZ[r] + bi1);
        gp[128 + lane] = f2bf(aN[r] + bi2);
    }
}

// ---- fused 6-step GRU, v4: gi precomputed; whh (bf16) in LDS; no per-t barrier
// 2 waves/block, each wave owns RB=8 nodes; lane = jj; grid = NN/(RB*2)
__global__ __launch_bounds__(128) void gru6_kernel(
        const unsigned short* __restrict__ gi,
        const unsigned* __restrict__ Wh01, const unsigned short* __restrict__ Whn,
        const float* __restrict__ bhh, float* __restrict__ hfinal) {
    __shared__ unsigned sW01[HH * HH];        // 16 KB
    __shared__ unsigned short sWn[HH * HH];   // 8 KB
    __shared__ float hs[2][RB][HH];           // 4 KB
    int tid = threadIdx.x;
    int wid = tid >> 6, lane = tid & 63;
    int nbase = (blockIdx.x * 2 + wid) * RB;

    for (int i = tid; i < HH * HH; i += 128) { sW01[i] = Wh01[i]; sWn[i] = Whn[i]; }
    __syncthreads();

    float h[RB];
#pragma unroll
    for (int r = 0; r < RB; ++r) { h[r] = 0.f; hs[wid][r][lane] = 0.f; }
    float bh0 = bhh[lane], bh1 = bhh[64 + lane], bh2 = bhh[128 + lane];

    for (int t = 0; t < TT; ++t) {
        float aR[RB], aZ[RB], aN[RB];
#pragma unroll
        for (int r = 0; r < RB; ++r) { aR[r] = aZ[r] = aN[r] = 0.f; }
        for (int k0 = 0; k0 < 16; ++k0) {
            float4 hv[RB];
#pragma unroll
            for (int r = 0; r < RB; ++r) hv[r] = *(const float4*)(&hs[wid][r][k0 << 2]);
#pragma unroll
            for (int u = 0; u < 4; ++u) {
                int k = k0 * 4 + u;
                unsigned w01 = sW01[(k << 6) + lane];
                float w_hr = bflo(w01), w_hz = bfhi(w01);
                float w_hn = bflo((unsigned)sWn[(k << 6) + lane]);
#pragma unroll
                for (int r = 0; r < RB; ++r) {
                    float hk = (u == 0) ? hv[r].x : (u == 1) ? hv[r].y
                             : (u == 2) ? hv[r].z : hv[r].w;
                    aR[r] = fmaf(hk, w_hr, aR[r]);
                    aZ[r] = fmaf(hk, w_hz, aZ[r]);
                    aN[r] = fmaf(hk, w_hn, aN[r]);
                }
            }
        }
        const unsigned short* gp = gi + ((size_t)t * NN + nbase) * 192;
#pragma unroll
        for (int r = 0; r < RB; ++r) {
            size_t gb = (size_t)r * 192;
            float gr = bflo((unsigned)gp[gb + lane]);
            float gz = bflo((unsigned)gp[gb + 64 + lane]);
            float gn = bflo((unsigned)gp[gb + 128 + lane]);
            float rr = 1.f / (1.f + expf(-(gr + aR[r] + bh0)));
            float zz = 1.f / (1.f + expf(-(gz + aZ[r] + bh1)));
            float nn_ = tanhf(gn + rr * (aN[r] + bh2));
            h[r] = (1.f - zz) * nn_ + zz * h[r];
            hs[wid][r][lane] = h[r];  // own-wave LDS, no cross-wave dep
        }
    }
#pragma unroll
    for (int r = 0; r < RB; ++r)
        hfinal[((size_t)(nbase + r) << 6) + lane] = h[r];
}

// ---- fused MLP head: out = sigmoid(relu(h@W3+b3)@W4 + b4) ---------------
__global__ void head_kernel(const float* __restrict__ h, const float* __restrict__ W3,
                            const float* __restrict__ b3, const float* __restrict__ W4,
                            const float* __restrict__ b4, float* __restrict__ out) {
    int nbase = blockIdx.x * RB;
    int lane = threadIdx.x;
    float acc[RB];
#pragma unroll
    for (int r = 0; r < RB; ++r) acc[r] = 0.f;
    for (int k0 = 0; k0 < 16; ++k0) {
        float4 hv[RB];
#pragma unroll
        for (int r = 0; r < RB; ++r)
            hv[r] = ((const float4*)(h + ((size_t)(nbase + r) << 6)))[k0];
#pragma unroll
        for (int u = 0; u < 4; ++u) {
            float w = W3[(k0 * 4 + u) * HH + lane];
#pragma unroll
            for (int r = 0; r < RB; ++r) {
                float hk = (u == 0) ? hv[r].x : (u == 1) ? hv[r].y : (u == 2) ? hv[r].z : hv[r].w;
                acc[r] = fmaf(hk, w, acc[r]);
            }
        }
    }
    float bb = b3[lane], w4 = W4[lane], b40 = b4[0];
#pragma unroll
    for (int r = 0; r < RB; ++r) {
        float v = acc[r] + bb;
        v = v > 0.f ? v : 0.f;
        float s = v * w4;
        s += __shfl_xor(s, 32); s += __shfl_xor(s, 16); s += __shfl_xor(s, 8);
        s += __shfl_xor(s, 4);  s += __shfl_xor(s, 2);  s += __shfl_xor(s, 1);
        if (lane == r) out[nbase + r] = 1.f / (1.f + expf(-(s + b40)));
    }
}

extern "C" void kernel_launch(void* const* d_in, const int* in_sizes, int n_in,
                              void* d_out, int out_size, void* d_ws, size_t ws_size,
                              hipStream_t stream) {
    const float* nf    = (const float*)d_in[0];
    const int*   edges = (const int*)  d_in[1];
    const float* W1  = (const float*)d_in[2];
    const float* b1  = (const float*)d_in[3];
    const float* W2  = (const float*)d_in[4];
    const float* b2  = (const float*)d_in[5];
    const float* wih = (const float*)d_in[6];
    const float* whh = (const float*)d_in[7];
    const float* bih = (const float*)d_in[8];
    const float* bhh = (const float*)d_in[9];
    const float* W3  = (const float*)d_in[10];
    const float* b3  = (const float*)d_in[11];
    const float* W4  = (const float*)d_in[12];
    const float* b4  = (const float*)d_in[13];
    float* out = (float*)d_out;

    // workspace layout
    int* wsi      = (int*)d_ws;
    int* cnt6     = wsi;                              // 6*NN
    int* gcur     = cnt6 + 6 * NN;                    // 6*NBKT (zeroed)
    int* rowptr6  = gcur + 6 * NBKT;                  // 6*(NN+1)
    int* col6     = rowptr6 + 6 * (NN + 1);           // 6*EE
    int* bucketArr= col6 + (size_t)6 * EE;            // 6*NBKT*CAP
    uintptr_t fbase = ((uintptr_t)(bucketArr + (size_t)6 * NBKT * CAP) + 15) & ~(uintptr_t)15;
    uint2* Wi     = (uint2*)fbase;                    // 4096 uint2 (32KB)
    unsigned* Wh01= (unsigned*)(Wi + HH * HH);        // 4096 uint (16KB)
    unsigned short* Whn = (unsigned short*)(Wh01 + HH * HH);  // 4096 ushort (8KB)
    float* dinv6 = (float*)(Whn + HH * HH);           // 6*NN
    float* Hf    = dinv6 + 6 * NN;                    // NN*HH (final h, fp32)
    unsigned short* Yb    = (unsigned short*)(Hf + (size_t)NN * HH);  // 6*NN*HH bf16
    unsigned short* Y2all = Yb + (size_t)6 * NN * HH;                 // 6*NN*HH bf16
    unsigned short* Zb1   = Y2all + (size_t)6 * NN * HH;              // 6*NN*HH bf16
    unsigned short* Zb2   = Zb1 + (size_t)6 * NN * HH;                // 6*NN*HH bf16
    unsigned short* gi    = Zb2 + (size_t)6 * NN * HH;                // 6*NN*192 bf16

    const int BS  = 256;
    const int gNH = (NN * HH + BS - 1) / BS;   // 5000
    const int gRB = NN / RB;                   // 2500
    const int gG6 = NN / (RB * 2);             // 1250
    const int gBIN = (EE + EPB - 1) / EPB;     // 157

    hipMemsetAsync(gcur, 0, 6 * NBKT * sizeof(int), stream);
    pack_gru_kernel<<<(HH * HH + BS - 1) / BS, BS, 0, stream>>>(wih, whh, Wi, Wh01, Whn);

    bin6_kernel<<<dim3(gBIN, TT), BS, 0, stream>>>(edges, gcur, bucketArr);
    bucket_count6_kernel<<<dim3(NBKT, TT), BS, 0, stream>>>(gcur, bucketArr, cnt6);
    scan6_kernel<<<TT, 1024, 0, stream>>>(cnt6, rowptr6, dinv6);
    regroup6_kernel<<<dim3(NBKT, TT), BS, 0, stream>>>(rowptr6, gcur, bucketArr, col6);
    y1all_kernel<<<dim3(gNH, TT), BS, 0, stream>>>(nf, W1, dinv6, Yb);

    // GCN layer 1 (all t) -> dense (all t) -> GCN layer 2 (all t)
    gather6_kernel<<<dim3(gNH, TT), BS, 0, stream>>>(rowptr6, col6, dinv6, Yb, b1, Zb1);
    y2all_kernel<<<dim3(gRB, TT), 64, 0, stream>>>(Zb1, W2, dinv6, Y2all);
    gather6_kernel<<<dim3(gNH, TT), BS, 0, stream>>>(rowptr6, col6, dinv6, Y2all, b2, Zb2);

    // gi = z@wihT + bih for all t (h-independent), then sequential h-only GRU
    giall_kernel<<<dim3(gRB, TT), 64, 0, stream>>>(Zb2, Wi, bih, gi);
    gru6_kernel<<<gG6, 128, 0, stream>>>(gi, Wh01, Whn, bhh, Hf);

    head_kernel<<<gRB, 64, 0, stream>>>(Hf, W3, b3, W4, b4, out);
}

// Round 17
// 526.191 us; speedup vs baseline: 1.7477x; 1.7477x over previous
//
#include <hip/hip_runtime.h>
#include <math.h>

static constexpr int NN   = 20000;
static constexpr int TT   = 6;
static constexpr int EE   = 640000;
static constexpr int CINC = 3;
static constexpr int HH   = 64;
static constexpr int RB   = 8;    // nodes per wave in the dense kernels
static constexpr int BKSH = 7;    // 128 nodes per bucket
static constexpr int NBKT = (NN + (1 << BKSH) - 1) >> BKSH;  // 157
static constexpr int CAP  = 6144; // bucket capacity (expected 4096, +32 sigma)
static constexpr int EPB  = 4096; // edges per workgroup in bin phase

// ---- bf16 helpers (storage = ushort) ------------------------------------
__device__ inline unsigned short f2bf(float f) {
    unsigned u = __float_as_uint(f);
    unsigned r = (u + 0x7FFFu + ((u >> 16) & 1u)) >> 16;  // RTNE
    return (unsigned short)r;
}
__device__ inline float bflo(unsigned u) { return __uint_as_float(u << 16); }
__device__ inline float bfhi(unsigned u) { return __uint_as_float(u & 0xFFFF0000u); }

// ---- phase 1: bin edges into 157 coarse buckets (packed dstLocal|src) ----
__global__ void bin6_kernel(const int* __restrict__ edges, int* __restrict__ gcur,
                            int* __restrict__ bucketArr) {
    int t = blockIdx.y;
    __shared__ int hist[NBKT];
    __shared__ int base[NBKT];
    int tid = threadIdx.x;
    for (int i = tid; i < NBKT; i += 256) hist[i] = 0;
    __syncthreads();
    const int* src = edges + (size_t)t * 2 * EE;
    const int* dst = src + EE;
    int e0 = blockIdx.x * EPB;
    int pack[16], loff[16], bkt[16];
    int m = 0;
#pragma unroll
    for (int i = 0; i < 16; ++i) {
        int e = e0 + tid + i * 256;
        if (e < EE) {
            int s = src[e], d = dst[e];
            int b = d >> BKSH;
            bkt[i] = b;
            pack[i] = ((d & 127) << 16) | s;
            loff[i] = atomicAdd(&hist[b], 1);
            m = i + 1;
        }
    }
    __syncthreads();
    for (int i = tid; i < NBKT; i += 256)
        base[i] = atomicAdd(&gcur[t * NBKT + i], hist[i]);
    __syncthreads();
    for (int i = 0; i < m; ++i) {
        int b = bkt[i];
        int pos = base[b] + loff[i];
        if (pos < CAP)
            bucketArr[(size_t)(t * NBKT + b) * CAP + pos] = pack[i];
    }
}

// ---- per-node degree from buckets: LDS histogram, coalesced write -------
__global__ void bucket_count6_kernel(const int* __restrict__ gcur,
                                     const int* __restrict__ bucketArr,
                                     int* __restrict__ cnt6) {
    int bk = blockIdx.x, t = blockIdx.y;
    __shared__ int hist[128];
    int tid = threadIdx.x;
    if (tid < 128) hist[tid] = 0;
    __syncthreads();
    int ecnt = gcur[t * NBKT + bk];
    if (ecnt > CAP) ecnt = CAP;
    const int* barr = bucketArr + (size_t)(t * NBKT + bk) * CAP;
    for (int e = tid; e < ecnt; e += 256) atomicAdd(&hist[barr[e] >> 16], 1);
    __syncthreads();
    int n = (bk << BKSH) + tid;
    if (tid < 128 && n < NN) cnt6[t * NN + n] = hist[tid];
}

// 6 blocks (one per t), 1024 threads: exclusive scan -> rowptr, plus dinv
__global__ void scan6_kernel(const int* __restrict__ cnt6, int* __restrict__ rowptr6,
                             float* __restrict__ dinv6) {
    int t = blockIdx.x;
    const int* cnt = cnt6 + t * NN;
    int* rowptr = rowptr6 + t * (NN + 1);
    float* dinv = dinv6 + t * NN;
    __shared__ int part[1024];
    const int CHUNK = 20;  // 1024*20 >= NN
    int tid = threadIdx.x;
    int base = tid * CHUNK;
    int local[CHUNK];
    int s = 0;
#pragma unroll
    for (int i = 0; i < CHUNK; ++i) {
        int idx = base + i;
        int v = (idx < NN) ? cnt[idx] : 0;
        local[i] = s;
        s += v;
    }
    part[tid] = s;
    __syncthreads();
    for (int off = 1; off < 1024; off <<= 1) {
        int v = part[tid];
        int add = (tid >= off) ? part[tid - off] : 0;
        __syncthreads();
        part[tid] = v + add;
        __syncthreads();
    }
    int ebase = (tid == 0) ? 0 : part[tid - 1];
#pragma unroll
    for (int i = 0; i < CHUNK; ++i) {
        int idx = base + i;
        if (idx < NN) {
            rowptr[idx] = ebase + local[i];
            dinv[idx] = rsqrtf((float)cnt[idx] + 1.0f);
        }
    }
    if (tid == 1023) rowptr[NN] = part[1023];
}

// ---- phase 2: in-LDS regroup of each bucket into per-node CSR segments ---
__global__ void regroup6_kernel(const int* __restrict__ rowptr6, const int* __restrict__ gcur,
                                const int* __restrict__ bucketArr, int* __restrict__ col6) {
    int bk = blockIdx.x, t = blockIdx.y;
    __shared__ int cursor[128];
    __shared__ int lcol[CAP];  // 24KB
    int tid = threadIdx.x;
    const int* rowptr = rowptr6 + t * (NN + 1);
    int nb0 = bk << BKSH;
    int base = rowptr[nb0];
    if (tid < 128) {
        int n = nb0 + tid;
        if (n < NN) cursor[tid] = rowptr[n] - base;
    }
    __syncthreads();
    int ecnt = gcur[t * NBKT + bk];
    if (ecnt > CAP) ecnt = CAP;
    const int* barr = bucketArr + (size_t)(t * NBKT + bk) * CAP;
    for (int e = tid; e < ecnt; e += 256) {
        int w = barr[e];
        int dl = w >> 16, s = w & 0xFFFF;
        int off = atomicAdd(&cursor[dl], 1);
        lcol[off] = s;
    }
    __syncthreads();
    int* colt = col6 + (size_t)t * EE + base;
    for (int e = tid; e < ecnt; e += 256) colt[e] = lcol[e];
}

// ---- GRU weight repack (bf16):
//   Wi[k*64+jj]  = uint2{ ir | iz<<16 , in }          (input-side, for giall)
//   Wh01[k*64+jj]= hr | hz<<16 ; Whn[k*64+jj] = hn    (hidden-side, for gru6)
__global__ void pack_gru_kernel(const float* __restrict__ wih, const float* __restrict__ whh,
                                uint2* __restrict__ Wi, unsigned* __restrict__ Wh01,
                                unsigned short* __restrict__ Whn) {
    int idx = blockIdx.x * blockDim.x + threadIdx.x;  // k*64 + jj
    if (idx >= HH * HH) return;
    int k = idx >> 6, jj = idx & 63;
    unsigned w_ir = f2bf(wih[jj * HH + k]);
    unsigned w_iz = f2bf(wih[(64 + jj) * HH + k]);
    unsigned w_in = f2bf(wih[(128 + jj) * HH + k]);
    unsigned w_hr = f2bf(whh[jj * HH + k]);
    unsigned w_hz = f2bf(whh[(64 + jj) * HH + k]);
    unsigned w_hn = f2bf(whh[(128 + jj) * HH + k]);
    Wi[idx] = make_uint2(w_ir | (w_iz << 16), w_in);
    Wh01[idx] = w_hr | (w_hz << 16);
    Whn[idx] = (unsigned short)w_hn;
}

// ---- y1 for ALL t: y = dinv * (x @ W1), bf16 out ------------------------
__global__ void y1all_kernel(const float* __restrict__ nf, const float* __restrict__ W1,
                             const float* __restrict__ dinv6, unsigned short* __restrict__ Yb) {
    int t = blockIdx.y;
    int gid = blockIdx.x * blockDim.x + threadIdx.x;
    if (gid >= NN * HH) return;
    int node = gid >> 6, hh = gid & 63;
    const float* xr = nf + (size_t)t * NN * CINC + node * CINC;
    float acc = 0.f;
#pragma unroll
    for (int k = 0; k < CINC; ++k) acc = fmaf(xr[k], W1[k * HH + hh], acc);
    Yb[(size_t)t * NN * HH + gid] = f2bf(dinv6[t * NN + node] * acc);
}

// ---- y2 for ALL t: y = dinv * (z @ W2), bf16 in/out ---------------------
__global__ void y2all_kernel(const unsigned short* __restrict__ Zb6, const float* __restrict__ W2,
                             const float* __restrict__ dinv6, unsigned short* __restrict__ Y2all) {
    int t = blockIdx.y;
    const unsigned short* z = Zb6 + (size_t)t * NN * HH;
    const float* dinv = dinv6 + t * NN;
    unsigned short* y = Y2all + (size_t)t * NN * HH;
    int nbase = blockIdx.x * RB;
    int lane = threadIdx.x;
    float acc[RB];
#pragma unroll
    for (int r = 0; r < RB; ++r) acc[r] = 0.f;
    for (int k0 = 0; k0 < 16; ++k0) {
        uint2 zv[RB];
#pragma unroll
        for (int r = 0; r < RB; ++r)
            zv[r] = *(const uint2*)(z + ((size_t)(nbase + r) << 6) + (k0 << 2));
#pragma unroll
        for (int u = 0; u < 4; ++u) {
            float w = W2[(k0 * 4 + u) * HH + lane];
#pragma unroll
            for (int r = 0; r < RB; ++r) {
                float zk = (u == 0) ? bflo(zv[r].x) : (u == 1) ? bfhi(zv[r].x)
                         : (u == 2) ? bflo(zv[r].y) : bfhi(zv[r].y);
                acc[r] = fmaf(zk, w, acc[r]);
            }
        }
    }
#pragma unroll
    for (int r = 0; r < RB; ++r)
        y[((size_t)(nbase + r) << 6) + lane] = f2bf(dinv[nbase + r] * acc[r]);
}

// ---- CSR gather for ALL t (bf16 rows -> bf16 z): z = relu(dinv*(sum+self)+b)
__global__ void gather6_kernel(const int* __restrict__ rowptr6, const int* __restrict__ col6,
                               const float* __restrict__ dinv6, const unsigned short* __restrict__ ybase,
                               const float* __restrict__ b, unsigned short* __restrict__ zbase) {
    int t = blockIdx.y;
    const int* rowptr = rowptr6 + t * (NN + 1);
    const int* col = col6 + (size_t)t * EE;
    const float* dinv = dinv6 + t * NN;
    const unsigned short* y = ybase + (size_t)t * NN * HH;
    unsigned short* z = zbase + (size_t)t * NN * HH;

    int node = (blockIdx.x * blockDim.x + threadIdx.x) >> 6;
    if (node >= NN) return;
    int lane = threadIdx.x & 63;
    int g = lane >> 3, q = lane & 7;
    int ps = rowptr[node], pe = rowptr[node + 1];
    float acc[8];
    if (g == 0) {  // self term
        const uint4 v = *(const uint4*)(y + ((size_t)node << 6) + (q << 3));
        acc[0] = bflo(v.x); acc[1] = bfhi(v.x);
        acc[2] = bflo(v.y); acc[3] = bfhi(v.y);
        acc[4] = bflo(v.z); acc[5] = bfhi(v.z);
        acc[6] = bflo(v.w); acc[7] = bfhi(v.w);
    } else {
#pragma unroll
        for (int j = 0; j < 8; ++j) acc[j] = 0.f;
    }
    for (int p = ps + g; p < pe; p += 8) {
        int c = col[p];
        const uint4 v = *(const uint4*)(y + ((size_t)c << 6) + (q << 3));
        acc[0] += bflo(v.x); acc[1] += bfhi(v.x);
        acc[2] += bflo(v.y); acc[3] += bfhi(v.y);
        acc[4] += bflo(v.z); acc[5] += bfhi(v.z);
        acc[6] += bflo(v.w); acc[7] += bfhi(v.w);
    }
#pragma unroll
    for (int j = 0; j < 8; ++j) {
        acc[j] += __shfl_xor(acc[j], 8);
        acc[j] += __shfl_xor(acc[j], 16);
        acc[j] += __shfl_xor(acc[j], 32);
    }
    if (g == 0) {
        float d = dinv[node];
        const float4 b0 = *(const float4*)(b + (q << 3));
        const float4 b1 = *(const float4*)(b + (q << 3) + 4);
        float o[8];
        o[0] = fmaf(d, acc[0], b0.x); o[1] = fmaf(d, acc[1], b0.y);
        o[2] = fmaf(d, acc[2], b0.z); o[3] = fmaf(d, acc[3], b0.w);
        o[4] = fmaf(d, acc[4], b1.x); o[5] = fmaf(d, acc[5], b1.y);
        o[6] = fmaf(d, acc[6], b1.z); o[7] = fmaf(d, acc[7], b1.w);
#pragma unroll
        for (int j = 0; j < 8; ++j) o[j] = o[j] > 0.f ? o[j] : 0.f;
        uint4 w;
        w.x = (unsigned)f2bf(o[0]) | ((unsigned)f2bf(o[1]) << 16);
        w.y = (unsigned)f2bf(o[2]) | ((unsigned)f2bf(o[3]) << 16);
        w.z = (unsigned)f2bf(o[4]) | ((unsigned)f2bf(o[5]) << 16);
        w.w = (unsigned)f2bf(o[6]) | ((unsigned)f2bf(o[7]) << 16);
        *(uint4*)(z + ((size_t)node << 6) + (q << 3)) = w;
    }
}

// ---- gi precompute for ALL t: gi[t][n][192] = z@wihT + bih (bf16) -------
// h-independent, fully parallel. One wave per RB nodes, lane = jj.
__global__ void giall_kernel(const unsigned short* __restrict__ Zb6, const uint2* __restrict__ Wi,
                             const float* __restrict__ bih, unsigned short* __restrict__ gi) {
    int t = blockIdx.y;
    const unsigned short* z = Zb6 + (size_t)t * NN * HH;
    int nbase = blockIdx.x * RB;
    int lane = threadIdx.x;
    float aR[RB], aZ[RB], aN[RB];
#pragma unroll
    for (int r = 0; r < RB; ++r) { aR[r] = aZ[r] = aN[r] = 0.f; }
    for (int k0 = 0; k0 < 16; ++k0) {
        uint2 zv[RB];
#pragma unroll
        for (int r = 0; r < RB; ++r)
            zv[r] = *(const uint2*)(z + ((size_t)(nbase + r) << 6) + (k0 << 2));
#pragma unroll
        for (int u = 0; u < 4; ++u) {
            uint2 w = Wi[((k0 * 4 + u) << 6) + lane];
            float w_ir = bflo(w.x), w_iz = bfhi(w.x), w_in = bflo(w.y);
#pragma unroll
            for (int r = 0; r < RB; ++r) {
                float zk = (u == 0) ? bflo(zv[r].x) : (u == 1) ? bfhi(zv[r].x)
                         : (u == 2) ? bflo(zv[r].y) : bfhi(zv[r].y);
                aR[r] = fmaf(zk, w_ir, aR[r]);
                aZ[r] = fmaf(zk, w_iz, aZ[r]);
                aN[r] = fmaf(zk, w_in, aN[r]);
            }
        }
    }
    float bi0 = bih[lane], bi1 = bih[64 + lane], bi2 = bih[128 + lane];
#pragma unroll
    for (int r = 0; r < RB; ++r) {
        unsigned short* gp = gi + ((size_t)t * NN + nbase + r) * 192;
        gp[lane]       = f2bf(aR[r] + bi0);
        gp[64 + lane]  = f2bf(aZ[r] + bi1);
        gp[128 + lane] = f2bf(aN[r] + bi2);
    }
}

// ---- fused 6-step GRU, v5: v4 + "#pragma unroll 1" on the t-loop --------
// (prevents cross-timestep gi-load hoisting that spilled v4 to scratch)
// 2 waves/block, each wave owns RB=8 nodes; lane = jj; grid = NN/(RB*2)
__global__ __launch_bounds__(128) void gru6_kernel(
        const unsigned short* __restrict__ gi,
        const unsigned* __restrict__ Wh01, const unsigned short* __restrict__ Whn,
        const float* __restrict__ bhh, float* __restrict__ hfinal) {
    __shared__ unsigned sW01[HH * HH];        // 16 KB
    __shared__ unsigned short sWn[HH * HH];   // 8 KB
    __shared__ float hs[2][RB][HH];           // 4 KB
    int tid = threadIdx.x;
    int wid = tid >> 6, lane = tid & 63;
    int nbase = (blockIdx.x * 2 + wid) * RB;

    for (int i = tid; i < HH * HH; i += 128) { sW01[i] = Wh01[i]; sWn[i] = Whn[i]; }
    __syncthreads();

#pragma unroll
    for (int r = 0; r < RB; ++r) hs[wid][r][lane] = 0.f;
    float bh0 = bhh[lane], bh1 = bhh[64 + lane], bh2 = bhh[128 + lane];

#pragma unroll 1
    for (int t = 0; t < TT; ++t) {
        float aR[RB], aZ[RB], aN[RB];
#pragma unroll
        for (int r = 0; r < RB; ++r) { aR[r] = aZ[r] = aN[r] = 0.f; }
#pragma unroll 1
        for (int k0 = 0; k0 < 16; ++k0) {
            float4 hv[RB];
#pragma unroll
            for (int r = 0; r < RB; ++r) hv[r] = *(const float4*)(&hs[wid][r][k0 << 2]);
#pragma unroll
            for (int u = 0; u < 4; ++u) {
                int k = k0 * 4 + u;
                unsigned w01 = sW01[(k << 6) + lane];
                float w_hr = bflo(w01), w_hz = bfhi(w01);
                float w_hn = bflo((unsigned)sWn[(k << 6) + lane]);
#pragma unroll
                for (int r = 0; r < RB; ++r) {
                    float hk = (u == 0) ? hv[r].x : (u == 1) ? hv[r].y
                             : (u == 2) ? hv[r].z : hv[r].w;
                    aR[r] = fmaf(hk, w_hr, aR[r]);
                    aZ[r] = fmaf(hk, w_hz, aZ[r]);
                    aN[r] = fmaf(hk, w_hn, aN[r]);
                }
            }
        }
        const unsigned short* gp = gi + ((size_t)t * NN + nbase) * 192;
#pragma unroll
        for (int r = 0; r < RB; ++r) {
            size_t gb = (size_t)r * 192;
            float gr = bflo((unsigned)gp[gb + lane]);
            float gz = bflo((unsigned)gp[gb + 64 + lane]);
            float gn = bflo((unsigned)gp[gb + 128 + lane]);
            float rr = 1.f / (1.f + expf(-(gr + aR[r] + bh0)));
            float zz = 1.f / (1.f + expf(-(gz + aZ[r] + bh1)));
            float nn_ = tanhf(gn + rr * (aN[r] + bh2));
            hs[wid][r][lane] = (1.f - zz) * nn_ + zz * hs[wid][r][lane];
        }
    }
#pragma unroll
    for (int r = 0; r < RB; ++r)
        hfinal[((size_t)(nbase + r) << 6) + lane] = hs[wid][r][lane];
}

// ---- fused MLP head: out = sigmoid(relu(h@W3+b3)@W4 + b4) ---------------
__global__ void head_kernel(const float* __restrict__ h, const float* __restrict__ W3,
                            const float* __restrict__ b3, const float* __restrict__ W4,
                            const float* __restrict__ b4, float* __restrict__ out) {
    int nbase = blockIdx.x * RB;
    int lane = threadIdx.x;
    float acc[RB];
#pragma unroll
    for (int r = 0; r < RB; ++r) acc[r] = 0.f;
    for (int k0 = 0; k0 < 16; ++k0) {
        float4 hv[RB];
#pragma unroll
        for (int r = 0; r < RB; ++r)
            hv[r] = ((const float4*)(h + ((size_t)(nbase + r) << 6)))[k0];
#pragma unroll
        for (int u = 0; u < 4; ++u) {
            float w = W3[(k0 * 4 + u) * HH + lane];
#pragma unroll
            for (int r = 0; r < RB; ++r) {
                float hk = (u == 0) ? hv[r].x : (u == 1) ? hv[r].y : (u == 2) ? hv[r].z : hv[r].w;
                acc[r] = fmaf(hk, w, acc[r]);
            }
        }
    }
    float bb = b3[lane], w4 = W4[lane], b40 = b4[0];
#pragma unroll
    for (int r = 0; r < RB; ++r) {
        float v = acc[r] + bb;
        v = v > 0.f ? v : 0.f;
        float s = v * w4;
        s += __shfl_xor(s, 32); s += __shfl_xor(s, 16); s += __shfl_xor(s, 8);
        s += __shfl_xor(s, 4);  s += __shfl_xor(s, 2);  s += __shfl_xor(s, 1);
        if (lane == r) out[nbase + r] = 1.f / (1.f + expf(-(s + b40)));
    }
}

extern "C" void kernel_launch(void* const* d_in, const int* in_sizes, int n_in,
                              void* d_out, int out_size, void* d_ws, size_t ws_size,
                              hipStream_t stream) {
    const float* nf    = (const float*)d_in[0];
    const int*   edges = (const int*)  d_in[1];
    const float* W1  = (const float*)d_in[2];
    const float* b1  = (const float*)d_in[3];
    const float* W2  = (const float*)d_in[4];
    const float* b2  = (const float*)d_in[5];
    const float* wih = (const float*)d_in[6];
    const float* whh = (const float*)d_in[7];
    const float* bih = (const float*)d_in[8];
    const float* bhh = (const float*)d_in[9];
    const float* W3  = (const float*)d_in[10];
    const float* b3  = (const float*)d_in[11];
    const float* W4  = (const float*)d_in[12];
    const float* b4  = (const float*)d_in[13];
    float* out = (float*)d_out;

    // workspace layout
    int* wsi      = (int*)d_ws;
    int* cnt6     = wsi;                              // 6*NN
    int* gcur     = cnt6 + 6 * NN;                    // 6*NBKT (zeroed)
    int* rowptr6  = gcur + 6 * NBKT;                  // 6*(NN+1)
    int* col6     = rowptr6 + 6 * (NN + 1);           // 6*EE
    int* bucketArr= col6 + (size_t)6 * EE;            // 6*NBKT*CAP
    uintptr_t fbase = ((uintptr_t)(bucketArr + (size_t)6 * NBKT * CAP) + 15) & ~(uintptr_t)15;
    uint2* Wi     = (uint2*)fbase;                    // 4096 uint2 (32KB)
    unsigned* Wh01= (unsigned*)(Wi + HH * HH);        // 4096 uint (16KB)
    unsigned short* Whn = (unsigned short*)(Wh01 + HH * HH);  // 4096 ushort (8KB)
    float* dinv6 = (float*)(Whn + HH * HH);           // 6*NN
    float* Hf    = dinv6 + 6 * NN;                    // NN*HH (final h, fp32)
    unsigned short* Yb    = (unsigned short*)(Hf + (size_t)NN * HH);  // 6*NN*HH bf16
    unsigned short* Y2all = Yb + (size_t)6 * NN * HH;                 // 6*NN*HH bf16
    unsigned short* Zb1   = Y2all + (size_t)6 * NN * HH;              // 6*NN*HH bf16
    unsigned short* Zb2   = Zb1 + (size_t)6 * NN * HH;                // 6*NN*HH bf16
    unsigned short* gi    = Zb2 + (size_t)6 * NN * HH;                // 6*NN*192 bf16

    const int BS  = 256;
    const int gNH = (NN * HH + BS - 1) / BS;   // 5000
    const int gRB = NN / RB;                   // 2500
    const int gG6 = NN / (RB * 2);             // 1250
    const int gBIN = (EE + EPB - 1) / EPB;     // 157

    hipMemsetAsync(gcur, 0, 6 * NBKT * sizeof(int), stream);
    pack_gru_kernel<<<(HH * HH + BS - 1) / BS, BS, 0, stream>>>(wih, whh, Wi, Wh01, Whn);

    bin6_kernel<<<dim3(gBIN, TT), BS, 0, stream>>>(edges, gcur, bucketArr);
    bucket_count6_kernel<<<dim3(NBKT, TT), BS, 0, stream>>>(gcur, bucketArr, cnt6);
    scan6_kernel<<<TT, 1024, 0, stream>>>(cnt6, rowptr6, dinv6);
    regroup6_kernel<<<dim3(NBKT, TT), BS, 0, stream>>>(rowptr6, gcur, bucketArr, col6);
    y1all_kernel<<<dim3(gNH, TT), BS, 0, stream>>>(nf, W1, dinv6, Yb);

    // GCN layer 1 (all t) -> dense (all t) -> GCN layer 2 (all t)
    gather6_kernel<<<dim3(gNH, TT), BS, 0, stream>>>(rowptr6, col6, dinv6, Yb, b1, Zb1);
    y2all_kernel<<<dim3(gRB, TT), 64, 0, stream>>>(Zb1, W2, dinv6, Y2all);
    gather6_kernel<<<dim3(gNH, TT), BS, 0, stream>>>(rowptr6, col6, dinv6, Y2all, b2, Zb2);

    // gi = z@wihT + bih for all t (h-independent), then sequential h-only GRU
    giall_kernel<<<dim3(gRB, TT), 64, 0, stream>>>(Zb2, Wi, bih, gi);
    gru6_kernel<<<gG6, 128, 0, stream>>>(gi, Wh01, Whn, bhh, Hf);

    head_kernel<<<gRB, 64, 0, stream>>>(Hf, W3, b3, W4, b4, out);
}

// Round 18
// 418.907 us; speedup vs baseline: 2.1953x; 1.2561x over previous
//
#include <hip/hip_runtime.h>
#include <math.h>

static constexpr int NN   = 20000;
static constexpr int TT   = 6;
static constexpr int EE   = 640000;
static constexpr int CINC = 3;
static constexpr int HH   = 64;
static constexpr int RB   = 8;    // nodes per wave in the dense kernels
static constexpr int BKSH = 7;    // 128 nodes per bucket
static constexpr int NBKT = (NN + (1 << BKSH) - 1) >> BKSH;  // 157
static constexpr int CAP  = 6144; // bucket capacity (expected 4096, +32 sigma)
static constexpr int EPB  = 4096; // edges per workgroup in bin phase

typedef __attribute__((ext_vector_type(8))) short bf16x8;
typedef __attribute__((ext_vector_type(4))) float f32x4;

// ---- bf16 helpers (storage = ushort) ------------------------------------
__device__ inline unsigned short f2bf(float f) {
    unsigned u = __float_as_uint(f);
    unsigned r = (u + 0x7FFFu + ((u >> 16) & 1u)) >> 16;  // RTNE
    return (unsigned short)r;
}
__device__ inline float bflo(unsigned u) { return __uint_as_float(u << 16); }
__device__ inline float bfhi(unsigned u) { return __uint_as_float(u & 0xFFFF0000u); }

// ---- phase 1: bin edges into 157 coarse buckets (packed dstLocal|src) ----
__global__ void bin6_kernel(const int* __restrict__ edges, int* __restrict__ gcur,
                            int* __restrict__ bucketArr) {
    int t = blockIdx.y;
    __shared__ int hist[NBKT];
    __shared__ int base[NBKT];
    int tid = threadIdx.x;
    for (int i = tid; i < NBKT; i += 256) hist[i] = 0;
    __syncthreads();
    const int* src = edges + (size_t)t * 2 * EE;
    const int* dst = src + EE;
    int e0 = blockIdx.x * EPB;
    int pack[16], loff[16], bkt[16];
    int m = 0;
#pragma unroll
    for (int i = 0; i < 16; ++i) {
        int e = e0 + tid + i * 256;
        if (e < EE) {
            int s = src[e], d = dst[e];
            int b = d >> BKSH;
            bkt[i] = b;
            pack[i] = ((d & 127) << 16) | s;
            loff[i] = atomicAdd(&hist[b], 1);
            m = i + 1;
        }
    }
    __syncthreads();
    for (int i = tid; i < NBKT; i += 256)
        base[i] = atomicAdd(&gcur[t * NBKT + i], hist[i]);
    __syncthreads();
    for (int i = 0; i < m; ++i) {
        int b = bkt[i];
        int pos = base[b] + loff[i];
        if (pos < CAP)
            bucketArr[(size_t)(t * NBKT + b) * CAP + pos] = pack[i];
    }
}

// ---- per-node degree from buckets: LDS histogram, coalesced write -------
__global__ void bucket_count6_kernel(const int* __restrict__ gcur,
                                     const int* __restrict__ bucketArr,
                                     int* __restrict__ cnt6) {
    int bk = blockIdx.x, t = blockIdx.y;
    __shared__ int hist[128];
    int tid = threadIdx.x;
    if (tid < 128) hist[tid] = 0;
    __syncthreads();
    int ecnt = gcur[t * NBKT + bk];
    if (ecnt > CAP) ecnt = CAP;
    const int* barr = bucketArr + (size_t)(t * NBKT + bk) * CAP;
    for (int e = tid; e < ecnt; e += 256) atomicAdd(&hist[barr[e] >> 16], 1);
    __syncthreads();
    int n = (bk << BKSH) + tid;
    if (tid < 128 && n < NN) cnt6[t * NN + n] = hist[tid];
}

// 6 blocks (one per t), 1024 threads: exclusive scan -> rowptr, plus dinv
__global__ void scan6_kernel(const int* __restrict__ cnt6, int* __restrict__ rowptr6,
                             float* __restrict__ dinv6) {
    int t = blockIdx.x;
    const int* cnt = cnt6 + t * NN;
    int* rowptr = rowptr6 + t * (NN + 1);
    float* dinv = dinv6 + t * NN;
    __shared__ int part[1024];
    const int CHUNK = 20;  // 1024*20 >= NN
    int tid = threadIdx.x;
    int base = tid * CHUNK;
    int local[CHUNK];
    int s = 0;
#pragma unroll
    for (int i = 0; i < CHUNK; ++i) {
        int idx = base + i;
        int v = (idx < NN) ? cnt[idx] : 0;
        local[i] = s;
        s += v;
    }
    part[tid] = s;
    __syncthreads();
    for (int off = 1; off < 1024; off <<= 1) {
        int v = part[tid];
        int add = (tid >= off) ? part[tid - off] : 0;
        __syncthreads();
        part[tid] = v + add;
        __syncthreads();
    }
    int ebase = (tid == 0) ? 0 : part[tid - 1];
#pragma unroll
    for (int i = 0; i < CHUNK; ++i) {
        int idx = base + i;
        if (idx < NN) {
            rowptr[idx] = ebase + local[i];
            dinv[idx] = rsqrtf((float)cnt[idx] + 1.0f);
        }
    }
    if (tid == 1023) rowptr[NN] = part[1023];
}

// ---- phase 2: in-LDS regroup of each bucket into per-node CSR segments ---
__global__ void regroup6_kernel(const int* __restrict__ rowptr6, const int* __restrict__ gcur,
                                const int* __restrict__ bucketArr, int* __restrict__ col6) {
    int bk = blockIdx.x, t = blockIdx.y;
    __shared__ int cursor[128];
    __shared__ int lcol[CAP];  // 24KB
    int tid = threadIdx.x;
    const int* rowptr = rowptr6 + t * (NN + 1);
    int nb0 = bk << BKSH;
    int base = rowptr[nb0];
    if (tid < 128) {
        int n = nb0 + tid;
        if (n < NN) cursor[tid] = rowptr[n] - base;
    }
    __syncthreads();
    int ecnt = gcur[t * NBKT + bk];
    if (ecnt > CAP) ecnt = CAP;
    const int* barr = bucketArr + (size_t)(t * NBKT + bk) * CAP;
    for (int e = tid; e < ecnt; e += 256) {
        int w = barr[e];
        int dl = w >> 16, s = w & 0xFFFF;
        int off = atomicAdd(&cursor[dl], 1);
        lcol[off] = s;
    }
    __syncthreads();
    int* colt = col6 + (size_t)t * EE + base;
    for (int e = tid; e < ecnt; e += 256) colt[e] = lcol[e];
}

// ---- hidden-side GRU weight repack (bf16) for gru6 ----------------------
__global__ void pack_gruh_kernel(const float* __restrict__ whh,
                                 unsigned* __restrict__ Wh01, unsigned short* __restrict__ Whn) {
    int idx = blockIdx.x * blockDim.x + threadIdx.x;  // k*64 + jj
    if (idx >= HH * HH) return;
    int k = idx >> 6, jj = idx & 63;
    unsigned w_hr = f2bf(whh[jj * HH + k]);
    unsigned w_hz = f2bf(whh[(64 + jj) * HH + k]);
    unsigned w_hn = f2bf(whh[(128 + jj) * HH + k]);
    Wh01[idx] = w_hr | (w_hz << 16);
    Whn[idx] = (unsigned short)w_hn;
}

// ---- MFMA B-fragment pack for giall: Bfrag[jt*2+kk][lane][e] = wih[j][k]
//   j = jt*16 + (lane&15), k = kk*32 + (lane>>4)*8 + e
__global__ void pack_bfrag_kernel(const float* __restrict__ wih,
                                  unsigned short* __restrict__ Bfrag) {
    int idx = blockIdx.x * blockDim.x + threadIdx.x;
    if (idx >= 24 * 64 * 8) return;
    int frag = idx >> 9;          // jt*2+kk
    int l    = (idx >> 3) & 63;
    int e    = idx & 7;
    int jt = frag >> 1, kk = frag & 1;
    int j = jt * 16 + (l & 15);
    int k = kk * 32 + ((l >> 4) << 3) + e;
    Bfrag[idx] = f2bf(wih[j * HH + k]);
}

// ---- y1 for ALL t: y = dinv * (x @ W1), bf16 out ------------------------
__global__ void y1all_kernel(const float* __restrict__ nf, const float* __restrict__ W1,
                             const float* __restrict__ dinv6, unsigned short* __restrict__ Yb) {
    int t = blockIdx.y;
    int gid = blockIdx.x * blockDim.x + threadIdx.x;
    if (gid >= NN * HH) return;
    int node = gid >> 6, hh = gid & 63;
    const float* xr = nf + (size_t)t * NN * CINC + node * CINC;
    float acc = 0.f;
#pragma unroll
    for (int k = 0; k < CINC; ++k) acc = fmaf(xr[k], W1[k * HH + hh], acc);
    Yb[(size_t)t * NN * HH + gid] = f2bf(dinv6[t * NN + node] * acc);
}

// ---- y2 for ALL t: y = dinv * (z @ W2), bf16 in/out ---------------------
__global__ void y2all_kernel(const unsigned short* __restrict__ Zb6, const float* __restrict__ W2,
                             const float* __restrict__ dinv6, unsigned short* __restrict__ Y2all) {
    int t = blockIdx.y;
    const unsigned short* z = Zb6 + (size_t)t * NN * HH;
    const float* dinv = dinv6 + t * NN;
    unsigned short* y = Y2all + (size_t)t * NN * HH;
    int nbase = blockIdx.x * RB;
    int lane = threadIdx.x;
    float acc[RB];
#pragma unroll
    for (int r = 0; r < RB; ++r) acc[r] = 0.f;
    for (int k0 = 0; k0 < 16; ++k0) {
        uint2 zv[RB];
#pragma unroll
        for (int r = 0; r < RB; ++r)
            zv[r] = *(const uint2*)(z + ((size_t)(nbase + r) << 6) + (k0 << 2));
#pragma unroll
        for (int u = 0; u < 4; ++u) {
            float w = W2[(k0 * 4 + u) * HH + lane];
#pragma unroll
            for (int r = 0; r < RB; ++r) {
                float zk = (u == 0) ? bflo(zv[r].x) : (u == 1) ? bfhi(zv[r].x)
                         : (u == 2) ? bflo(zv[r].y) : bfhi(zv[r].y);
                acc[r] = fmaf(zk, w, acc[r]);
            }
        }
    }
#pragma unroll
    for (int r = 0; r < RB; ++r)
        y[((size_t)(nbase + r) << 6) + lane] = f2bf(dinv[nbase + r] * acc[r]);
}

// ---- CSR gather for ALL t (bf16 rows -> bf16 z): z = relu(dinv*(sum+self)+b)
__global__ void gather6_kernel(const int* __restrict__ rowptr6, const int* __restrict__ col6,
                               const float* __restrict__ dinv6, const unsigned short* __restrict__ ybase,
                               const float* __restrict__ b, unsigned short* __restrict__ zbase) {
    int t = blockIdx.y;
    const int* rowptr = rowptr6 + t * (NN + 1);
    const int* col = col6 + (size_t)t * EE;
    const float* dinv = dinv6 + t * NN;
    const unsigned short* y = ybase + (size_t)t * NN * HH;
    unsigned short* z = zbase + (size_t)t * NN * HH;

    int node = (blockIdx.x * blockDim.x + threadIdx.x) >> 6;
    if (node >= NN) return;
    int lane = threadIdx.x & 63;
    int g = lane >> 3, q = lane & 7;
    int ps = rowptr[node], pe = rowptr[node + 1];
    float acc[8];
    if (g == 0) {  // self term
        const uint4 v = *(const uint4*)(y + ((size_t)node << 6) + (q << 3));
        acc[0] = bflo(v.x); acc[1] = bfhi(v.x);
        acc[2] = bflo(v.y); acc[3] = bfhi(v.y);
        acc[4] = bflo(v.z); acc[5] = bfhi(v.z);
        acc[6] = bflo(v.w); acc[7] = bfhi(v.w);
    } else {
#pragma unroll
        for (int j = 0; j < 8; ++j) acc[j] = 0.f;
    }
    for (int p = ps + g; p < pe; p += 8) {
        int c = col[p];
        const uint4 v = *(const uint4*)(y + ((size_t)c << 6) + (q << 3));
        acc[0] += bflo(v.x); acc[1] += bfhi(v.x);
        acc[2] += bflo(v.y); acc[3] += bfhi(v.y);
        acc[4] += bflo(v.z); acc[5] += bfhi(v.z);
        acc[6] += bflo(v.w); acc[7] += bfhi(v.w);
    }
#pragma unroll
    for (int j = 0; j < 8; ++j) {
        acc[j] += __shfl_xor(acc[j], 8);
        acc[j] += __shfl_xor(acc[j], 16);
        acc[j] += __shfl_xor(acc[j], 32);
    }
    if (g == 0) {
        float d = dinv[node];
        const float4 b0 = *(const float4*)(b + (q << 3));
        const float4 b1 = *(const float4*)(b + (q << 3) + 4);
        float o[8];
        o[0] = fmaf(d, acc[0], b0.x); o[1] = fmaf(d, acc[1], b0.y);
        o[2] = fmaf(d, acc[2], b0.z); o[3] = fmaf(d, acc[3], b0.w);
        o[4] = fmaf(d, acc[4], b1.x); o[5] = fmaf(d, acc[5], b1.y);
        o[6] = fmaf(d, acc[6], b1.z); o[7] = fmaf(d, acc[7], b1.w);
#pragma unroll
        for (int j = 0; j < 8; ++j) o[j] = o[j] > 0.f ? o[j] : 0.f;
        uint4 w;
        w.x = (unsigned)f2bf(o[0]) | ((unsigned)f2bf(o[1]) << 16);
        w.y = (unsigned)f2bf(o[2]) | ((unsigned)f2bf(o[3]) << 16);
        w.z = (unsigned)f2bf(o[4]) | ((unsigned)f2bf(o[5]) << 16);
        w.w = (unsigned)f2bf(o[6]) | ((unsigned)f2bf(o[7]) << 16);
        *(uint4*)(z + ((size_t)node << 6) + (q << 3)) = w;
    }
}

// ---- gi via MFMA: gi[m][j] = (Zb6 @ wihT)[m][j] + bih[j], m = t*NN+n ----
// one wave per 16-row tile; 12 jt tiles of 16 cols; K=64 = 2 chained MFMA.
__global__ __launch_bounds__(256) void giall_mfma_kernel(
        const unsigned short* __restrict__ Zb6, const unsigned short* __restrict__ Bfrag,
        const float* __restrict__ bih, unsigned short* __restrict__ gi) {
    int w = threadIdx.x >> 6, lane = threadIdx.x & 63;
    int tile = blockIdx.x * 4 + w;
    int m0 = tile << 4;
    int r16 = lane & 15, kg = lane >> 4;
    // A fragments: lane holds Z[m0 + r16][kk*32 + kg*8 .. +7]
    const unsigned short* zrow = Zb6 + ((size_t)(m0 + r16) << 6) + (kg << 3);
    bf16x8 a0 = *(const bf16x8*)zrow;
    bf16x8 a1 = *(const bf16x8*)(zrow + 32);
    f32x4 acc[12];
#pragma unroll
    for (int jt = 0; jt < 12; ++jt) {
        bf16x8 b0 = *(const bf16x8*)(Bfrag + ((size_t)((jt << 1) + 0) << 9) + (lane << 3));
        bf16x8 b1 = *(const bf16x8*)(Bfrag + ((size_t)((jt << 1) + 1) << 9) + (lane << 3));
        f32x4 c = {0.f, 0.f, 0.f, 0.f};
        c = __builtin_amdgcn_mfma_f32_16x16x32_bf16(a0, b0, c, 0, 0, 0);
        c = __builtin_amdgcn_mfma_f32_16x16x32_bf16(a1, b1, c, 0, 0, 0);
        acc[jt] = c;
    }
    // D layout: col = lane&15, row = (lane>>4)*4 + reg
#pragma unroll
    for (int jt = 0; jt < 12; ++jt) {
        float bi = bih[jt * 16 + r16];
#pragma unroll
        for (int reg = 0; reg < 4; ++reg) {
            int node = m0 + (kg << 2) + reg;
            gi[(size_t)node * 192 + jt * 16 + r16] = f2bf(acc[jt][reg] + bi);
        }
    }
}

// ---- fused 6-step GRU, v5 (unchanged): gi precomputed; bf16 whh in LDS --
__global__ __launch_bounds__(128) void gru6_kernel(
        const unsigned short* __restrict__ gi,
        const unsigned* __restrict__ Wh01, const unsigned short* __restrict__ Whn,
        const float* __restrict__ bhh, float* __restrict__ hfinal) {
    __shared__ unsigned sW01[HH * HH];        // 16 KB
    __shared__ unsigned short sWn[HH * HH];   // 8 KB
    __shared__ float hs[2][RB][HH];           // 4 KB
    int tid = threadIdx.x;
    int wid = tid >> 6, lane = tid & 63;
    int nbase = (blockIdx.x * 2 + wid) * RB;

    for (int i = tid; i < HH * HH; i += 128) { sW01[i] = Wh01[i]; sWn[i] = Whn[i]; }
    __syncthreads();

#pragma unroll
    for (int r = 0; r < RB; ++r) hs[wid][r][lane] = 0.f;
    float bh0 = bhh[lane], bh1 = bhh[64 + lane], bh2 = bhh[128 + lane];

#pragma unroll 1
    for (int t = 0; t < TT; ++t) {
        float aR[RB], aZ[RB], aN[RB];
#pragma unroll
        for (int r = 0; r < RB; ++r) { aR[r] = aZ[r] = aN[r] = 0.f; }
#pragma unroll 1
        for (int k0 = 0; k0 < 16; ++k0) {
            float4 hv[RB];
#pragma unroll
            for (int r = 0; r < RB; ++r) hv[r] = *(const float4*)(&hs[wid][r][k0 << 2]);
#pragma unroll
            for (int u = 0; u < 4; ++u) {
                int k = k0 * 4 + u;
                unsigned w01 = sW01[(k << 6) + lane];
                float w_hr = bflo(w01), w_hz = bfhi(w01);
                float w_hn = bflo((unsigned)sWn[(k << 6) + lane]);
#pragma unroll
                for (int r = 0; r < RB; ++r) {
                    float hk = (u == 0) ? hv[r].x : (u == 1) ? hv[r].y
                             : (u == 2) ? hv[r].z : hv[r].w;
                    aR[r] = fmaf(hk, w_hr, aR[r]);
                    aZ[r] = fmaf(hk, w_hz, aZ[r]);
                    aN[r] = fmaf(hk, w_hn, aN[r]);
                }
            }
        }
        const unsigned short* gp = gi + ((size_t)t * NN + nbase) * 192;
#pragma unroll
        for (int r = 0; r < RB; ++r) {
            size_t gb = (size_t)r * 192;
            float gr = bflo((unsigned)gp[gb + lane]);
            float gz = bflo((unsigned)gp[gb + 64 + lane]);
            float gn = bflo((unsigned)gp[gb + 128 + lane]);
            float rr = 1.f / (1.f + expf(-(gr + aR[r] + bh0)));
            float zz = 1.f / (1.f + expf(-(gz + aZ[r] + bh1)));
            float nn_ = tanhf(gn + rr * (aN[r] + bh2));
            hs[wid][r][lane] = (1.f - zz) * nn_ + zz * hs[wid][r][lane];
        }
    }
#pragma unroll
    for (int r = 0; r < RB; ++r)
        hfinal[((size_t)(nbase + r) << 6) + lane] = hs[wid][r][lane];
}

// ---- fused MLP head: out = sigmoid(relu(h@W3+b3)@W4 + b4) ---------------
__global__ void head_kernel(const float* __restrict__ h, const float* __restrict__ W3,
                            const float* __restrict__ b3, const float* __restrict__ W4,
                            const float* __restrict__ b4, float* __restrict__ out) {
    int nbase = blockIdx.x * RB;
    int lane = threadIdx.x;
    float acc[RB];
#pragma unroll
    for (int r = 0; r < RB; ++r) acc[r] = 0.f;
    for (int k0 = 0; k0 < 16; ++k0) {
        float4 hv[RB];
#pragma unroll
        for (int r = 0; r < RB; ++r)
            hv[r] = ((const float4*)(h + ((size_t)(nbase + r) << 6)))[k0];
#pragma unroll
        for (int u = 0; u < 4; ++u) {
            float w = W3[(k0 * 4 + u) * HH + lane];
#pragma unroll
            for (int r = 0; r < RB; ++r) {
                float hk = (u == 0) ? hv[r].x : (u == 1) ? hv[r].y : (u == 2) ? hv[r].z : hv[r].w;
                acc[r] = fmaf(hk, w, acc[r]);
            }
        }
    }
    float bb = b3[lane], w4 = W4[lane], b40 = b4[0];
#pragma unroll
    for (int r = 0; r < RB; ++r) {
        float v = acc[r] + bb;
        v = v > 0.f ? v : 0.f;
        float s = v * w4;
        s += __shfl_xor(s, 32); s += __shfl_xor(s, 16); s += __shfl_xor(s, 8);
        s += __shfl_xor(s, 4);  s += __shfl_xor(s, 2);  s += __shfl_xor(s, 1);
        if (lane == r) out[nbase + r] = 1.f / (1.f + expf(-(s + b40)));
    }
}

extern "C" void kernel_launch(void* const* d_in, const int* in_sizes, int n_in,
                              void* d_out, int out_size, void* d_ws, size_t ws_size,
                              hipStream_t stream) {
    const float* nf    = (const float*)d_in[0];
    const int*   edges = (const int*)  d_in[1];
    const float* W1  = (const float*)d_in[2];
    const float* b1  = (const float*)d_in[3];
    const float* W2  = (const float*)d_in[4];
    const float* b2  = (const float*)d_in[5];
    const float* wih = (const float*)d_in[6];
    const float* whh = (const float*)d_in[7];
    const float* bih = (const float*)d_in[8];
    const float* bhh = (const float*)d_in[9];
    const float* W3  = (const float*)d_in[10];
    const float* b3  = (const float*)d_in[11];
    const float* W4  = (const float*)d_in[12];
    const float* b4  = (const float*)d_in[13];
    float* out = (float*)d_out;

    // workspace layout
    int* wsi      = (int*)d_ws;
    int* cnt6     = wsi;                              // 6*NN
    int* gcur     = cnt6 + 6 * NN;                    // 6*NBKT (zeroed)
    int* rowptr6  = gcur + 6 * NBKT;                  // 6*(NN+1)
    int* col6     = rowptr6 + 6 * (NN + 1);           // 6*EE
    int* bucketArr= col6 + (size_t)6 * EE;            // 6*NBKT*CAP
    uintptr_t fbase = ((uintptr_t)(bucketArr + (size_t)6 * NBKT * CAP) + 15) & ~(uintptr_t)15;
    unsigned short* Bfrag = (unsigned short*)fbase;   // 24*64*8 bf16 (24KB)
    unsigned* Wh01= (unsigned*)(Bfrag + 24 * 64 * 8); // 4096 uint (16KB)
    unsigned short* Whn = (unsigned short*)(Wh01 + HH * HH);  // 4096 ushort (8KB)
    float* dinv6 = (float*)(Whn + HH * HH);           // 6*NN
    float* Hf    = dinv6 + 6 * NN;                    // NN*HH (final h, fp32)
    unsigned short* Yb    = (unsigned short*)(Hf + (size_t)NN * HH);  // 6*NN*HH bf16
    unsigned short* Y2all = Yb + (size_t)6 * NN * HH;                 // 6*NN*HH bf16
    unsigned short* Zb1   = Y2all + (size_t)6 * NN * HH;              // 6*NN*HH bf16
    unsigned short* Zb2   = Zb1 + (size_t)6 * NN * HH;                // 6*NN*HH bf16
    unsigned short* gi    = Zb2 + (size_t)6 * NN * HH;                // 6*NN*192 bf16

    const int BS  = 256;
    const int gNH = (NN * HH + BS - 1) / BS;   // 5000
    const int gRB = NN / RB;                   // 2500
    const int gG6 = NN / (RB * 2);             // 1250
    const int gMM = (TT * NN) / 64;            // 1875 (MFMA: 4 waves x 16 rows)
    const int gBIN = (EE + EPB - 1) / EPB;     // 157

    hipMemsetAsync(gcur, 0, 6 * NBKT * sizeof(int), stream);
    pack_gruh_kernel<<<(HH * HH + BS - 1) / BS, BS, 0, stream>>>(whh, Wh01, Whn);
    pack_bfrag_kernel<<<(24 * 64 * 8 + BS - 1) / BS, BS, 0, stream>>>(wih, Bfrag);

    bin6_kernel<<<dim3(gBIN, TT), BS, 0, stream>>>(edges, gcur, bucketArr);
    bucket_count6_kernel<<<dim3(NBKT, TT), BS, 0, stream>>>(gcur, bucketArr, cnt6);
    scan6_kernel<<<TT, 1024, 0, stream>>>(cnt6, rowptr6, dinv6);
    regroup6_kernel<<<dim3(NBKT, TT), BS, 0, stream>>>(rowptr6, gcur, bucketArr, col6);
    y1all_kernel<<<dim3(gNH, TT), BS, 0, stream>>>(nf, W1, dinv6, Yb);

    // GCN layer 1 (all t) -> dense (all t) -> GCN layer 2 (all t)
    gather6_kernel<<<dim3(gNH, TT), BS, 0, stream>>>(rowptr6, col6, dinv6, Yb, b1, Zb1);
    y2all_kernel<<<dim3(gRB, TT), 64, 0, stream>>>(Zb1, W2, dinv6, Y2all);
    gather6_kernel<<<dim3(gNH, TT), BS, 0, stream>>>(rowptr6, col6, dinv6, Y2all, b2, Zb2);

    // gi = Zb2 @ wihT + bih for all t via MFMA, then sequential h-only GRU
    giall_mfma_kernel<<<gMM, 256, 0, stream>>>(Zb2, Bfrag, bih, gi);
    gru6_kernel<<<gG6, 128, 0, stream>>>(gi, Wh01, Whn, bhh, Hf);

    head_kernel<<<gRB, 64, 0, stream>>>(Hf, W3, b3, W4, b4, out);
}

// Round 19
// 319.328 us; speedup vs baseline: 2.8799x; 1.3118x over previous
//
#include <hip/hip_runtime.h>
#include <math.h>

static constexpr int NN   = 20000;
static constexpr int TT   = 6;
static constexpr int EE   = 640000;
static constexpr int CINC = 3;
static constexpr int HH   = 64;
static constexpr int RB   = 8;    // nodes per wave in the dense kernels
static constexpr int BKSH = 7;    // 128 nodes per bucket
static constexpr int NBKT = (NN + (1 << BKSH) - 1) >> BKSH;  // 157
static constexpr int CAP  = 6144; // bucket capacity (expected 4096, +32 sigma)
static constexpr int EPB  = 4096; // edges per workgroup in bin phase

typedef __attribute__((ext_vector_type(8))) short bf16x8;
typedef __attribute__((ext_vector_type(4))) float f32x4;

// ---- bf16 helpers (storage = ushort) ------------------------------------
__device__ inline unsigned short f2bf(float f) {
    unsigned u = __float_as_uint(f);
    unsigned r = (u + 0x7FFFu + ((u >> 16) & 1u)) >> 16;  // RTNE
    return (unsigned short)r;
}
__device__ inline float bflo(unsigned u) { return __uint_as_float(u << 16); }
__device__ inline float bfhi(unsigned u) { return __uint_as_float(u & 0xFFFF0000u); }

// fast transcendentals (gru6 only): v_exp/v_rcp based
__device__ inline float fsig(float x) {
    return __builtin_amdgcn_rcpf(1.f + __expf(-x));
}
__device__ inline float ftanh(float x) {
    x = fminf(fmaxf(x, -15.f), 15.f);
    float e = __expf(2.f * x);
    return (e - 1.f) * __builtin_amdgcn_rcpf(e + 1.f);
}

// ---- phase 1: bin edges into 157 coarse buckets (packed dstLocal|src) ----
__global__ void bin6_kernel(const int* __restrict__ edges, int* __restrict__ gcur,
                            int* __restrict__ bucketArr) {
    int t = blockIdx.y;
    __shared__ int hist[NBKT];
    __shared__ int base[NBKT];
    int tid = threadIdx.x;
    for (int i = tid; i < NBKT; i += 256) hist[i] = 0;
    __syncthreads();
    const int* src = edges + (size_t)t * 2 * EE;
    const int* dst = src + EE;
    int e0 = blockIdx.x * EPB;
    int pack[16], loff[16], bkt[16];
    int m = 0;
#pragma unroll
    for (int i = 0; i < 16; ++i) {
        int e = e0 + tid + i * 256;
        if (e < EE) {
            int s = src[e], d = dst[e];
            int b = d >> BKSH;
            bkt[i] = b;
            pack[i] = ((d & 127) << 16) | s;
            loff[i] = atomicAdd(&hist[b], 1);
            m = i + 1;
        }
    }
    __syncthreads();
    for (int i = tid; i < NBKT; i += 256)
        base[i] = atomicAdd(&gcur[t * NBKT + i], hist[i]);
    __syncthreads();
    for (int i = 0; i < m; ++i) {
        int b = bkt[i];
        int pos = base[b] + loff[i];
        if (pos < CAP)
            bucketArr[(size_t)(t * NBKT + b) * CAP + pos] = pack[i];
    }
}

// ---- tiny per-t exclusive scan of bucket counts -> bucket edge bases ----
__global__ void scan_gcur_kernel(const int* __restrict__ gcur, int* __restrict__ gbase,
                                 int* __restrict__ rowptr6) {
    int t = blockIdx.x;
    __shared__ int sv[NBKT];
    int tid = threadIdx.x;
    if (tid < NBKT) sv[tid] = gcur[t * NBKT + tid];
    __syncthreads();
    if (tid == 0) {
        int s = 0;
        for (int i = 0; i < NBKT; ++i) { int v = sv[i]; sv[i] = s; s += v; }
        rowptr6[t * (NN + 1) + NN] = EE;
    }
    __syncthreads();
    if (tid < NBKT) gbase[t * NBKT + tid] = sv[tid];
}

// ---- merged: per-bucket hist + scan -> rowptr/dinv/cursor, then regroup --
__global__ void regroup6_kernel(const int* __restrict__ gcur, const int* __restrict__ gbase,
                                const int* __restrict__ bucketArr, int* __restrict__ rowptr6,
                                float* __restrict__ dinv6, int* __restrict__ col6) {
    int bk = blockIdx.x, t = blockIdx.y;
    __shared__ int hist[128];
    __shared__ int lscan[128];
    __shared__ int cursor[128];
    __shared__ int lcol[CAP];  // 24KB
    int tid = threadIdx.x;
    if (tid < 128) hist[tid] = 0;
    __syncthreads();
    int ecnt = gcur[t * NBKT + bk];
    if (ecnt > CAP) ecnt = CAP;
    const int* barr = bucketArr + (size_t)(t * NBKT + bk) * CAP;
    for (int e = tid; e < ecnt; e += 256) atomicAdd(&hist[barr[e] >> 16], 1);
    __syncthreads();
    // inclusive scan of hist (128 entries)
    if (tid < 128) lscan[tid] = hist[tid];
    __syncthreads();
    for (int off = 1; off < 128; off <<= 1) {
        int v = 0, a = 0;
        if (tid < 128) { v = lscan[tid]; a = (tid >= off) ? lscan[tid - off] : 0; }
        __syncthreads();
        if (tid < 128) lscan[tid] = v + a;
        __syncthreads();
    }
    int base = gbase[t * NBKT + bk];
    int nb0 = bk << BKSH;
    if (tid < 128) {
        int excl = lscan[tid] - hist[tid];
        cursor[tid] = excl;
        int n = nb0 + tid;
        if (n < NN) {
            rowptr6[t * (NN + 1) + n] = base + excl;
            dinv6[t * NN + n] = rsqrtf((float)hist[tid] + 1.0f);
        }
    }
    __syncthreads();
    for (int e = tid; e < ecnt; e += 256) {
        int w = barr[e];
        int dl = w >> 16, s = w & 0xFFFF;
        int off = atomicAdd(&cursor[dl], 1);
        lcol[off] = s;
    }
    __syncthreads();
    int* colt = col6 + (size_t)t * EE + base;
    for (int e = tid; e < ecnt; e += 256) colt[e] = lcol[e];
}

// ---- hidden-side GRU weight repack (bf16) for gru6 ----------------------
__global__ void pack_gruh_kernel(const float* __restrict__ whh,
                                 unsigned* __restrict__ Wh01, unsigned short* __restrict__ Whn) {
    int idx = blockIdx.x * blockDim.x + threadIdx.x;  // k*64 + jj
    if (idx >= HH * HH) return;
    int k = idx >> 6, jj = idx & 63;
    unsigned w_hr = f2bf(whh[jj * HH + k]);
    unsigned w_hz = f2bf(whh[(64 + jj) * HH + k]);
    unsigned w_hn = f2bf(whh[(128 + jj) * HH + k]);
    Wh01[idx] = w_hr | (w_hz << 16);
    Whn[idx] = (unsigned short)w_hn;
}

// ---- MFMA B-fragment pack (wih, 24 frags): j = jt*16+(l&15), k = kk*32+(l>>4)*8+e
__global__ void pack_bfrag_kernel(const float* __restrict__ wih,
                                  unsigned short* __restrict__ Bfrag) {
    int idx = blockIdx.x * blockDim.x + threadIdx.x;
    if (idx >= 24 * 64 * 8) return;
    int frag = idx >> 9;
    int l    = (idx >> 3) & 63;
    int e    = idx & 7;
    int jt = frag >> 1, kk = frag & 1;
    int j = jt * 16 + (l & 15);
    int k = kk * 32 + ((l >> 4) << 3) + e;
    Bfrag[idx] = f2bf(wih[j * HH + k]);
}

// ---- MFMA B-fragment pack (W2, 8 frags): B[k][j] = W2[k*HH+j] -----------
__global__ void pack_bfrag2_kernel(const float* __restrict__ W2,
                                   unsigned short* __restrict__ Bfrag2) {
    int idx = blockIdx.x * blockDim.x + threadIdx.x;
    if (idx >= 8 * 64 * 8) return;
    int frag = idx >> 9;
    int l    = (idx >> 3) & 63;
    int e    = idx & 7;
    int jt = frag >> 1, kk = frag & 1;
    int j = jt * 16 + (l & 15);
    int k = kk * 32 + ((l >> 4) << 3) + e;
    Bfrag2[idx] = f2bf(W2[k * HH + j]);
}

// ---- y1 for ALL t: y = dinv * (x @ W1), bf16 out ------------------------
__global__ void y1all_kernel(const float* __restrict__ nf, const float* __restrict__ W1,
                             const float* __restrict__ dinv6, unsigned short* __restrict__ Yb) {
    int t = blockIdx.y;
    int gid = blockIdx.x * blockDim.x + threadIdx.x;
    if (gid >= NN * HH) return;
    int node = gid >> 6, hh = gid & 63;
    const float* xr = nf + (size_t)t * NN * CINC + node * CINC;
    float acc = 0.f;
#pragma unroll
    for (int k = 0; k < CINC; ++k) acc = fmaf(xr[k], W1[k * HH + hh], acc);
    Yb[(size_t)t * NN * HH + gid] = f2bf(dinv6[t * NN + node] * acc);
}

// ---- y2 via MFMA: Y2[m][j] = dinv6[m] * (Zb1 @ W2)[m][j] ----------------
__global__ __launch_bounds__(256) void y2all_mfma_kernel(
        const unsigned short* __restrict__ Zb1, const unsigned short* __restrict__ Bfrag2,
        const float* __restrict__ dinv6, unsigned short* __restrict__ Y2all) {
    int w = threadIdx.x >> 6, lane = threadIdx.x & 63;
    int tile = blockIdx.x * 4 + w;
    int m0 = tile << 4;
    int r16 = lane & 15, kg = lane >> 4;
    const unsigned short* zrow = Zb1 + ((size_t)(m0 + r16) << 6) + (kg << 3);
    bf16x8 a0 = *(const bf16x8*)zrow;
    bf16x8 a1 = *(const bf16x8*)(zrow + 32);
    f32x4 acc[4];
#pragma unroll
    for (int jt = 0; jt < 4; ++jt) {
        bf16x8 b0 = *(const bf16x8*)(Bfrag2 + ((size_t)((jt << 1) + 0) << 9) + (lane << 3));
        bf16x8 b1 = *(const bf16x8*)(Bfrag2 + ((size_t)((jt << 1) + 1) << 9) + (lane << 3));
        f32x4 c = {0.f, 0.f, 0.f, 0.f};
        c = __builtin_amdgcn_mfma_f32_16x16x32_bf16(a0, b0, c, 0, 0, 0);
        c = __builtin_amdgcn_mfma_f32_16x16x32_bf16(a1, b1, c, 0, 0, 0);
        acc[jt] = c;
    }
#pragma unroll
    for (int jt = 0; jt < 4; ++jt) {
#pragma unroll
        for (int reg = 0; reg < 4; ++reg) {
            int m = m0 + (kg << 2) + reg;
            Y2all[((size_t)m << 6) + jt * 16 + r16] = f2bf(acc[jt][reg] * dinv6[m]);
        }
    }
}

// ---- CSR gather for ALL t (bf16 rows -> bf16 z): z = relu(dinv*(sum+self)+b)
__global__ void gather6_kernel(const int* __restrict__ rowptr6, const int* __restrict__ col6,
                               const float* __restrict__ dinv6, const unsigned short* __restrict__ ybase,
                               const float* __restrict__ b, unsigned short* __restrict__ zbase) {
    int t = blockIdx.y;
    const int* rowptr = rowptr6 + t * (NN + 1);
    const int* col = col6 + (size_t)t * EE;
    const float* dinv = dinv6 + t * NN;
    const unsigned short* y = ybase + (size_t)t * NN * HH;
    unsigned short* z = zbase + (size_t)t * NN * HH;

    int node = (blockIdx.x * blockDim.x + threadIdx.x) >> 6;
    if (node >= NN) return;
    int lane = threadIdx.x & 63;
    int g = lane >> 3, q = lane & 7;
    int ps = rowptr[node], pe = rowptr[node + 1];
    float acc[8];
    if (g == 0) {  // self term
        const uint4 v = *(const uint4*)(y + ((size_t)node << 6) + (q << 3));
        acc[0] = bflo(v.x); acc[1] = bfhi(v.x);
        acc[2] = bflo(v.y); acc[3] = bfhi(v.y);
        acc[4] = bflo(v.z); acc[5] = bfhi(v.z);
        acc[6] = bflo(v.w); acc[7] = bfhi(v.w);
    } else {
#pragma unroll
        for (int j = 0; j < 8; ++j) acc[j] = 0.f;
    }
    for (int p = ps + g; p < pe; p += 8) {
        int c = col[p];
        const uint4 v = *(const uint4*)(y + ((size_t)c << 6) + (q << 3));
        acc[0] += bflo(v.x); acc[1] += bfhi(v.x);
        acc[2] += bflo(v.y); acc[3] += bfhi(v.y);
        acc[4] += bflo(v.z); acc[5] += bfhi(v.z);
        acc[6] += bflo(v.w); acc[7] += bfhi(v.w);
    }
#pragma unroll
    for (int j = 0; j < 8; ++j) {
        acc[j] += __shfl_xor(acc[j], 8);
        acc[j] += __shfl_xor(acc[j], 16);
        acc[j] += __shfl_xor(acc[j], 32);
    }
    if (g == 0) {
        float d = dinv[node];
        const float4 b0 = *(const float4*)(b + (q << 3));
        const float4 b1 = *(const float4*)(b + (q << 3) + 4);
        float o[8];
        o[0] = fmaf(d, acc[0], b0.x); o[1] = fmaf(d, acc[1], b0.y);
        o[2] = fmaf(d, acc[2], b0.z); o[3] = fmaf(d, acc[3], b0.w);
        o[4] = fmaf(d, acc[4], b1.x); o[5] = fmaf(d, acc[5], b1.y);
        o[6] = fmaf(d, acc[6], b1.z); o[7] = fmaf(d, acc[7], b1.w);
#pragma unroll
        for (int j = 0; j < 8; ++j) o[j] = o[j] > 0.f ? o[j] : 0.f;
        uint4 w;
        w.x = (unsigned)f2bf(o[0]) | ((unsigned)f2bf(o[1]) << 16);
        w.y = (unsigned)f2bf(o[2]) | ((unsigned)f2bf(o[3]) << 16);
        w.z = (unsigned)f2bf(o[4]) | ((unsigned)f2bf(o[5]) << 16);
        w.w = (unsigned)f2bf(o[6]) | ((unsigned)f2bf(o[7]) << 16);
        *(uint4*)(z + ((size_t)node << 6) + (q << 3)) = w;
    }
}

// ---- gi via MFMA: gi[m][j] = (Zb2 @ wihT)[m][j] + bih[j] ----------------
__global__ __launch_bounds__(256) void giall_mfma_kernel(
        const unsigned short* __restrict__ Zb6, const unsigned short* __restrict__ Bfrag,
        const float* __restrict__ bih, unsigned short* __restrict__ gi) {
    int w = threadIdx.x >> 6, lane = threadIdx.x & 63;
    int tile = blockIdx.x * 4 + w;
    int m0 = tile << 4;
    int r16 = lane & 15, kg = lane >> 4;
    const unsigned short* zrow = Zb6 + ((size_t)(m0 + r16) << 6) + (kg << 3);
    bf16x8 a0 = *(const bf16x8*)zrow;
    bf16x8 a1 = *(const bf16x8*)(zrow + 32);
    f32x4 acc[12];
#pragma unroll
    for (int jt = 0; jt < 12; ++jt) {
        bf16x8 b0 = *(const bf16x8*)(Bfrag + ((size_t)((jt << 1) + 0) << 9) + (lane << 3));
        bf16x8 b1 = *(const bf16x8*)(Bfrag + ((size_t)((jt << 1) + 1) << 9) + (lane << 3));
        f32x4 c = {0.f, 0.f, 0.f, 0.f};
        c = __builtin_amdgcn_mfma_f32_16x16x32_bf16(a0, b0, c, 0, 0, 0);
        c = __builtin_amdgcn_mfma_f32_16x16x32_bf16(a1, b1, c, 0, 0, 0);
        acc[jt] = c;
    }
#pragma unroll
    for (int jt = 0; jt < 12; ++jt) {
        float bi = bih[jt * 16 + r16];
#pragma unroll
        for (int reg = 0; reg < 4; ++reg) {
            int node = m0 + (kg << 2) + reg;
            gi[(size_t)node * 192 + jt * 16 + r16] = f2bf(acc[jt][reg] + bi);
        }
    }
}

// ---- fused 6-step GRU (v5 + fast transcendentals) -----------------------
__global__ __launch_bounds__(128) void gru6_kernel(
        const unsigned short* __restrict__ gi,
        const unsigned* __restrict__ Wh01, const unsigned short* __restrict__ Whn,
        const float* __restrict__ bhh, float* __restrict__ hfinal) {
    __shared__ unsigned sW01[HH * HH];        // 16 KB
    __shared__ unsigned short sWn[HH * HH];   // 8 KB
    __shared__ float hs[2][RB][HH];           // 4 KB
    int tid = threadIdx.x;
    int wid = tid >> 6, lane = tid & 63;
    int nbase = (blockIdx.x * 2 + wid) * RB;

    for (int i = tid; i < HH * HH; i += 128) { sW01[i] = Wh01[i]; sWn[i] = Whn[i]; }
    __syncthreads();

#pragma unroll
    for (int r = 0; r < RB; ++r) hs[wid][r][lane] = 0.f;
    float bh0 = bhh[lane], bh1 = bhh[64 + lane], bh2 = bhh[128 + lane];

#pragma unroll 1
    for (int t = 0; t < TT; ++t) {
        float aR[RB], aZ[RB], aN[RB];
#pragma unroll
        for (int r = 0; r < RB; ++r) { aR[r] = aZ[r] = aN[r] = 0.f; }
#pragma unroll 1
        for (int k0 = 0; k0 < 16; ++k0) {
            float4 hv[RB];
#pragma unroll
            for (int r = 0; r < RB; ++r) hv[r] = *(const float4*)(&hs[wid][r][k0 << 2]);
#pragma unroll
            for (int u = 0; u < 4; ++u) {
                int k = k0 * 4 + u;
                unsigned w01 = sW01[(k << 6) + lane];
                float w_hr = bflo(w01), w_hz = bfhi(w01);
                float w_hn = bflo((unsigned)sWn[(k << 6) + lane]);
#pragma unroll
                for (int r = 0; r < RB; ++r) {
                    float hk = (u == 0) ? hv[r].x : (u == 1) ? hv[r].y
                             : (u == 2) ? hv[r].z : hv[r].w;
                    aR[r] = fmaf(hk, w_hr, aR[r]);
                    aZ[r] = fmaf(hk, w_hz, aZ[r]);
                    aN[r] = fmaf(hk, w_hn, aN[r]);
                }
            }
        }
        const unsigned short* gp = gi + ((size_t)t * NN + nbase) * 192;
#pragma unroll
        for (int r = 0; r < RB; ++r) {
            size_t gb = (size_t)r * 192;
            float gr = bflo((unsigned)gp[gb + lane]);
            float gz = bflo((unsigned)gp[gb + 64 + lane]);
            float gn = bflo((unsigned)gp[gb + 128 + lane]);
            float rr = fsig(gr + aR[r] + bh0);
            float zz = fsig(gz + aZ[r] + bh1);
            float nn_ = ftanh(gn + rr * (aN[r] + bh2));
            hs[wid][r][lane] = (1.f - zz) * nn_ + zz * hs[wid][r][lane];
        }
    }
#pragma unroll
    for (int r = 0; r < RB; ++r)
        hfinal[((size_t)(nbase + r) << 6) + lane] = hs[wid][r][lane];
}

// ---- fused MLP head: out = sigmoid(relu(h@W3+b3)@W4 + b4) ---------------
__global__ void head_kernel(const float* __restrict__ h, const float* __restrict__ W3,
                            const float* __restrict__ b3, const float* __restrict__ W4,
                            const float* __restrict__ b4, float* __restrict__ out) {
    int nbase = blockIdx.x * RB;
    int lane = threadIdx.x;
    float acc[RB];
#pragma unroll
    for (int r = 0; r < RB; ++r) acc[r] = 0.f;
    for (int k0 = 0; k0 < 16; ++k0) {
        float4 hv[RB];
#pragma unroll
        for (int r = 0; r < RB; ++r)
            hv[r] = ((const float4*)(h + ((size_t)(nbase + r) << 6)))[k0];
#pragma unroll
        for (int u = 0; u < 4; ++u) {
            float w = W3[(k0 * 4 + u) * HH + lane];
#pragma unroll
            for (int r = 0; r < RB; ++r) {
                float hk = (u == 0) ? hv[r].x : (u == 1) ? hv[r].y : (u == 2) ? hv[r].z : hv[r].w;
                acc[r] = fmaf(hk, w, acc[r]);
            }
        }
    }
    float bb = b3[lane], w4 = W4[lane], b40 = b4[0];
#pragma unroll
    for (int r = 0; r < RB; ++r) {
        float v = acc[r] + bb;
        v = v > 0.f ? v : 0.f;
        float s = v * w4;
        s += __shfl_xor(s, 32); s += __shfl_xor(s, 16); s += __shfl_xor(s, 8);
        s += __shfl_xor(s, 4);  s += __shfl_xor(s, 2);  s += __shfl_xor(s, 1);
        if (lane == r) out[nbase + r] = 1.f / (1.f + expf(-(s + b40)));
    }
}

extern "C" void kernel_launch(void* const* d_in, const int* in_sizes, int n_in,
                              void* d_out, int out_size, void* d_ws, size_t ws_size,
                              hipStream_t stream) {
    const float* nf    = (const float*)d_in[0];
    const int*   edges = (const int*)  d_in[1];
    const float* W1  = (const float*)d_in[2];
    const float* b1  = (const float*)d_in[3];
    const float* W2  = (const float*)d_in[4];
    const float* b2  = (const float*)d_in[5];
    const float* wih = (const float*)d_in[6];
    const float* whh = (const float*)d_in[7];
    const float* bih = (const float*)d_in[8];
    const float* bhh = (const float*)d_in[9];
    const float* W3  = (const float*)d_in[10];
    const float* b3  = (const float*)d_in[11];
    const float* W4  = (const float*)d_in[12];
    const float* b4  = (const float*)d_in[13];
    float* out = (float*)d_out;

    // workspace layout
    int* wsi      = (int*)d_ws;
    int* gcur     = wsi;                              // 6*NBKT (zeroed)
    int* gbase    = gcur + 6 * NBKT;                  // 6*NBKT
    int* rowptr6  = gbase + 6 * NBKT;                 // 6*(NN+1)
    int* col6     = rowptr6 + 6 * (NN + 1);           // 6*EE
    int* bucketArr= col6 + (size_t)6 * EE;            // 6*NBKT*CAP
    uintptr_t fbase = ((uintptr_t)(bucketArr + (size_t)6 * NBKT * CAP) + 15) & ~(uintptr_t)15;
    unsigned short* Bfrag = (unsigned short*)fbase;   // 24*64*8 bf16
    unsigned short* Bfrag2= Bfrag + 24 * 64 * 8;      // 8*64*8 bf16
    unsigned* Wh01= (unsigned*)(Bfrag2 + 8 * 64 * 8); // 4096 uint
    unsigned short* Whn = (unsigned short*)(Wh01 + HH * HH);  // 4096 ushort
    float* dinv6 = (float*)(Whn + HH * HH);           // 6*NN
    float* Hf    = dinv6 + 6 * NN;                    // NN*HH (final h, fp32)
    unsigned short* Yb    = (unsigned short*)(Hf + (size_t)NN * HH);  // 6*NN*HH bf16
    unsigned short* Y2all = Yb + (size_t)6 * NN * HH;                 // 6*NN*HH bf16
    unsigned short* Zb1   = Y2all + (size_t)6 * NN * HH;              // 6*NN*HH bf16
    unsigned short* Zb2   = Zb1 + (size_t)6 * NN * HH;                // 6*NN*HH bf16
    unsigned short* gi    = Zb2 + (size_t)6 * NN * HH;                // 6*NN*192 bf16

    const int BS  = 256;
    const int gNH = (NN * HH + BS - 1) / BS;   // 5000
    const int gRB = NN / RB;                   // 2500
    const int gG6 = NN / (RB * 2);             // 1250
    const int gMM = (TT * NN) / 64;            // 1875
    const int gBIN = (EE + EPB - 1) / EPB;     // 157

    hipMemsetAsync(gcur, 0, 6 * NBKT * sizeof(int), stream);
    pack_gruh_kernel<<<(HH * HH + BS - 1) / BS, BS, 0, stream>>>(whh, Wh01, Whn);
    pack_bfrag_kernel<<<(24 * 64 * 8 + BS - 1) / BS, BS, 0, stream>>>(wih, Bfrag);
    pack_bfrag2_kernel<<<(8 * 64 * 8 + BS - 1) / BS, BS, 0, stream>>>(W2, Bfrag2);

    bin6_kernel<<<dim3(gBIN, TT), BS, 0, stream>>>(edges, gcur, bucketArr);
    scan_gcur_kernel<<<TT, BS, 0, stream>>>(gcur, gbase, rowptr6);
    regroup6_kernel<<<dim3(NBKT, TT), BS, 0, stream>>>(gcur, gbase, bucketArr,
                                                       rowptr6, dinv6, col6);
    y1all_kernel<<<dim3(gNH, TT), BS, 0, stream>>>(nf, W1, dinv6, Yb);

    // GCN layer 1 (all t) -> dense via MFMA (all t) -> GCN layer 2 (all t)
    gather6_kernel<<<dim3(gNH, TT), BS, 0, stream>>>(rowptr6, col6, dinv6, Yb, b1, Zb1);
    y2all_mfma_kernel<<<gMM, 256, 0, stream>>>(Zb1, Bfrag2, dinv6, Y2all);
    gather6_kernel<<<dim3(gNH, TT), BS, 0, stream>>>(rowptr6, col6, dinv6, Y2all, b2, Zb2);

    // gi = Zb2 @ wihT + bih via MFMA, then sequential h-only GRU
    giall_mfma_kernel<<<gMM, 256, 0, stream>>>(Zb2, Bfrag, bih, gi);
    gru6_kernel<<<gG6, 128, 0, stream>>>(gi, Wh01, Whn, bhh, Hf);

    head_kernel<<<gRB, 64, 0, stream>>>(Hf, W3, b3, W4, b4, out);
}

// Round 20
// 312.892 us; speedup vs baseline: 2.9391x; 1.0206x over previous
//
#include <hip/hip_runtime.h>
#include <math.h>

static constexpr int NN   = 20000;
static constexpr int TT   = 6;
static constexpr int EE   = 640000;
static constexpr int CINC = 3;
static constexpr int HH   = 64;
static constexpr int RB   = 8;    // nodes per wave (y1/head)
static constexpr int RBG  = 4;    // nodes per wave in gru6
static constexpr int BKSH = 7;    // 128 nodes per bucket
static constexpr int NBKT = (NN + (1 << BKSH) - 1) >> BKSH;  // 157
static constexpr int CAP  = 6144; // bucket capacity (expected 4096, +32 sigma)
static constexpr int EPB  = 4096; // edges per workgroup in bin phase

typedef __attribute__((ext_vector_type(8))) short bf16x8;
typedef __attribute__((ext_vector_type(4))) float f32x4;

// ---- bf16 helpers (storage = ushort) ------------------------------------
__device__ inline unsigned short f2bf(float f) {
    unsigned u = __float_as_uint(f);
    unsigned r = (u + 0x7FFFu + ((u >> 16) & 1u)) >> 16;  // RTNE
    return (unsigned short)r;
}
__device__ inline float bflo(unsigned u) { return __uint_as_float(u << 16); }
__device__ inline float bfhi(unsigned u) { return __uint_as_float(u & 0xFFFF0000u); }

// fast transcendentals (gru6 only)
__device__ inline float fsig(float x) {
    return __builtin_amdgcn_rcpf(1.f + __expf(-x));
}
__device__ inline float ftanh(float x) {
    x = fminf(fmaxf(x, -15.f), 15.f);
    float e = __expf(2.f * x);
    return (e - 1.f) * __builtin_amdgcn_rcpf(e + 1.f);
}

// ---- phase 1: bin edges into 157 coarse buckets (packed dstLocal|src) ----
__global__ void bin6_kernel(const int* __restrict__ edges, int* __restrict__ gcur,
                            int* __restrict__ bucketArr) {
    int t = blockIdx.y;
    __shared__ int hist[NBKT];
    __shared__ int base[NBKT];
    int tid = threadIdx.x;
    for (int i = tid; i < NBKT; i += 256) hist[i] = 0;
    __syncthreads();
    const int* src = edges + (size_t)t * 2 * EE;
    const int* dst = src + EE;
    int e0 = blockIdx.x * EPB;
    int pack[16], loff[16], bkt[16];
    int m = 0;
#pragma unroll
    for (int i = 0; i < 16; ++i) {
        int e = e0 + tid + i * 256;
        if (e < EE) {
            int s = src[e], d = dst[e];
            int b = d >> BKSH;
            bkt[i] = b;
            pack[i] = ((d & 127) << 16) | s;
            loff[i] = atomicAdd(&hist[b], 1);
            m = i + 1;
        }
    }
    __syncthreads();
    for (int i = tid; i < NBKT; i += 256)
        base[i] = atomicAdd(&gcur[t * NBKT + i], hist[i]);
    __syncthreads();
    for (int i = 0; i < m; ++i) {
        int b = bkt[i];
        int pos = base[b] + loff[i];
        if (pos < CAP)
            bucketArr[(size_t)(t * NBKT + b) * CAP + pos] = pack[i];
    }
}

// ---- tiny per-t exclusive scan of bucket counts -> bucket edge bases ----
__global__ void scan_gcur_kernel(const int* __restrict__ gcur, int* __restrict__ gbase,
                                 int* __restrict__ rowptr6) {
    int t = blockIdx.x;
    __shared__ int sv[NBKT];
    int tid = threadIdx.x;
    if (tid < NBKT) sv[tid] = gcur[t * NBKT + tid];
    __syncthreads();
    if (tid == 0) {
        int s = 0;
        for (int i = 0; i < NBKT; ++i) { int v = sv[i]; sv[i] = s; s += v; }
        rowptr6[t * (NN + 1) + NN] = EE;
    }
    __syncthreads();
    if (tid < NBKT) gbase[t * NBKT + tid] = sv[tid];
}

// ---- merged: per-bucket hist + scan -> rowptr/dinv/cursor, then regroup --
__global__ void regroup6_kernel(const int* __restrict__ gcur, const int* __restrict__ gbase,
                                const int* __restrict__ bucketArr, int* __restrict__ rowptr6,
                                float* __restrict__ dinv6, int* __restrict__ col6) {
    int bk = blockIdx.x, t = blockIdx.y;
    __shared__ int hist[128];
    __shared__ int lscan[128];
    __shared__ int cursor[128];
    __shared__ int lcol[CAP];  // 24KB
    int tid = threadIdx.x;
    if (tid < 128) hist[tid] = 0;
    __syncthreads();
    int ecnt = gcur[t * NBKT + bk];
    if (ecnt > CAP) ecnt = CAP;
    const int* barr = bucketArr + (size_t)(t * NBKT + bk) * CAP;
    for (int e = tid; e < ecnt; e += 256) atomicAdd(&hist[barr[e] >> 16], 1);
    __syncthreads();
    if (tid < 128) lscan[tid] = hist[tid];
    __syncthreads();
    for (int off = 1; off < 128; off <<= 1) {
        int v = 0, a = 0;
        if (tid < 128) { v = lscan[tid]; a = (tid >= off) ? lscan[tid - off] : 0; }
        __syncthreads();
        if (tid < 128) lscan[tid] = v + a;
        __syncthreads();
    }
    int base = gbase[t * NBKT + bk];
    int nb0 = bk << BKSH;
    if (tid < 128) {
        int excl = lscan[tid] - hist[tid];
        cursor[tid] = excl;
        int n = nb0 + tid;
        if (n < NN) {
            rowptr6[t * (NN + 1) + n] = base + excl;
            dinv6[t * NN + n] = rsqrtf((float)hist[tid] + 1.0f);
        }
    }
    __syncthreads();
    for (int e = tid; e < ecnt; e += 256) {
        int w = barr[e];
        int dl = w >> 16, s = w & 0xFFFF;
        int off = atomicAdd(&cursor[dl], 1);
        lcol[off] = s;
    }
    __syncthreads();
    int* colt = col6 + (size_t)t * EE + base;
    for (int e = tid; e < ecnt; e += 256) colt[e] = lcol[e];
}

// ---- hidden-side GRU weight repack (bf16) for gru6 ----------------------
__global__ void pack_gruh_kernel(const float* __restrict__ whh,
                                 unsigned* __restrict__ Wh01, unsigned short* __restrict__ Whn) {
    int idx = blockIdx.x * blockDim.x + threadIdx.x;  // k*64 + jj
    if (idx >= HH * HH) return;
    int k = idx >> 6, jj = idx & 63;
    unsigned w_hr = f2bf(whh[jj * HH + k]);
    unsigned w_hz = f2bf(whh[(64 + jj) * HH + k]);
    unsigned w_hn = f2bf(whh[(128 + jj) * HH + k]);
    Wh01[idx] = w_hr | (w_hz << 16);
    Whn[idx] = (unsigned short)w_hn;
}

// ---- MFMA B-fragment pack (wih, 24 frags) -------------------------------
__global__ void pack_bfrag_kernel(const float* __restrict__ wih,
                                  unsigned short* __restrict__ Bfrag) {
    int idx = blockIdx.x * blockDim.x + threadIdx.x;
    if (idx >= 24 * 64 * 8) return;
    int frag = idx >> 9;
    int l    = (idx >> 3) & 63;
    int e    = idx & 7;
    int jt = frag >> 1, kk = frag & 1;
    int j = jt * 16 + (l & 15);
    int k = kk * 32 + ((l >> 4) << 3) + e;
    Bfrag[idx] = f2bf(wih[j * HH + k]);
}

// ---- MFMA B-fragment pack (W2, 8 frags): B[k][j] = W2[k*HH+j] -----------
__global__ void pack_bfrag2_kernel(const float* __restrict__ W2,
                                   unsigned short* __restrict__ Bfrag2) {
    int idx = blockIdx.x * blockDim.x + threadIdx.x;
    if (idx >= 8 * 64 * 8) return;
    int frag = idx >> 9;
    int l    = (idx >> 3) & 63;
    int e    = idx & 7;
    int jt = frag >> 1, kk = frag & 1;
    int j = jt * 16 + (l & 15);
    int k = kk * 32 + ((l >> 4) << 3) + e;
    Bfrag2[idx] = f2bf(W2[k * HH + j]);
}

// ---- y1 for ALL t: y = dinv * (x @ W1), bf16 out ------------------------
__global__ void y1all_kernel(const float* __restrict__ nf, const float* __restrict__ W1,
                             const float* __restrict__ dinv6, unsigned short* __restrict__ Yb) {
    int t = blockIdx.y;
    int gid = blockIdx.x * blockDim.x + threadIdx.x;
    if (gid >= NN * HH) return;
    int node = gid >> 6, hh = gid & 63;
    const float* xr = nf + (size_t)t * NN * CINC + node * CINC;
    float acc = 0.f;
#pragma unroll
    for (int k = 0; k < CINC; ++k) acc = fmaf(xr[k], W1[k * HH + hh], acc);
    Yb[(size_t)t * NN * HH + gid] = f2bf(dinv6[t * NN + node] * acc);
}

// ---- y2 via MFMA: Y2[m][j] = dinv6[m] * (Zb1 @ W2)[m][j] ----------------
__global__ __launch_bounds__(256) void y2all_mfma_kernel(
        const unsigned short* __restrict__ Zb1, const unsigned short* __restrict__ Bfrag2,
        const float* __restrict__ dinv6, unsigned short* __restrict__ Y2all) {
    int w = threadIdx.x >> 6, lane = threadIdx.x & 63;
    int tile = blockIdx.x * 4 + w;
    int m0 = tile << 4;
    int r16 = lane & 15, kg = lane >> 4;
    const unsigned short* zrow = Zb1 + ((size_t)(m0 + r16) << 6) + (kg << 3);
    bf16x8 a0 = *(const bf16x8*)zrow;
    bf16x8 a1 = *(const bf16x8*)(zrow + 32);
    f32x4 acc[4];
#pragma unroll
    for (int jt = 0; jt < 4; ++jt) {
        bf16x8 b0 = *(const bf16x8*)(Bfrag2 + ((size_t)((jt << 1) + 0) << 9) + (lane << 3));
        bf16x8 b1 = *(const bf16x8*)(Bfrag2 + ((size_t)((jt << 1) + 1) << 9) + (lane << 3));
        f32x4 c = {0.f, 0.f, 0.f, 0.f};
        c = __builtin_amdgcn_mfma_f32_16x16x32_bf16(a0, b0, c, 0, 0, 0);
        c = __builtin_amdgcn_mfma_f32_16x16x32_bf16(a1, b1, c, 0, 0, 0);
        acc[jt] = c;
    }
#pragma unroll
    for (int jt = 0; jt < 4; ++jt) {
#pragma unroll
        for (int reg = 0; reg < 4; ++reg) {
            int m = m0 + (kg << 2) + reg;
            Y2all[((size_t)m << 6) + jt * 16 + r16] = f2bf(acc[jt][reg] * dinv6[m]);
        }
    }
}

// ---- CSR gather for ALL t (bf16 rows -> bf16 z), 32-bit voffset loads ----
__global__ void gather6_kernel(const int* __restrict__ rowptr6, const int* __restrict__ col6,
                               const float* __restrict__ dinv6, const unsigned short* __restrict__ ybase,
                               const float* __restrict__ b, unsigned short* __restrict__ zbase) {
    int t = blockIdx.y;
    const int* rowptr = rowptr6 + t * (NN + 1);
    const int* col = col6 + (size_t)t * EE;
    const float* dinv = dinv6 + t * NN;
    const unsigned char* y = (const unsigned char*)(ybase + (size_t)t * NN * HH);
    unsigned short* z = zbase + (size_t)t * NN * HH;

    int node = (blockIdx.x * blockDim.x + threadIdx.x) >> 6;
    if (node >= NN) return;
    int lane = threadIdx.x & 63;
    int g = lane >> 3, q = lane & 7;
    int ps = rowptr[node], pe = rowptr[node + 1];
    unsigned qoff = (unsigned)q << 4;
    float acc[8];
    if (g == 0) {  // self term
        const uint4 v = *(const uint4*)(y + (((unsigned)node << 7) + qoff));
        acc[0] = bflo(v.x); acc[1] = bfhi(v.x);
        acc[2] = bflo(v.y); acc[3] = bfhi(v.y);
        acc[4] = bflo(v.z); acc[5] = bfhi(v.z);
        acc[6] = bflo(v.w); acc[7] = bfhi(v.w);
    } else {
#pragma unroll
        for (int j = 0; j < 8; ++j) acc[j] = 0.f;
    }
    for (int p = ps + g; p < pe; p += 8) {
        unsigned c = (unsigned)col[p];
        const uint4 v = *(const uint4*)(y + ((c << 7) + qoff));
        acc[0] += bflo(v.x); acc[1] += bfhi(v.x);
        acc[2] += bflo(v.y); acc[3] += bfhi(v.y);
        acc[4] += bflo(v.z); acc[5] += bfhi(v.z);
        acc[6] += bflo(v.w); acc[7] += bfhi(v.w);
    }
#pragma unroll
    for (int j = 0; j < 8; ++j) {
        acc[j] += __shfl_xor(acc[j], 8);
        acc[j] += __shfl_xor(acc[j], 16);
        acc[j] += __shfl_xor(acc[j], 32);
    }
    if (g == 0) {
        float d = dinv[node];
        const float4 b0 = *(const float4*)(b + (q << 3));
        const float4 b1 = *(const float4*)(b + (q << 3) + 4);
        float o[8];
        o[0] = fmaf(d, acc[0], b0.x); o[1] = fmaf(d, acc[1], b0.y);
        o[2] = fmaf(d, acc[2], b0.z); o[3] = fmaf(d, acc[3], b0.w);
        o[4] = fmaf(d, acc[4], b1.x); o[5] = fmaf(d, acc[5], b1.y);
        o[6] = fmaf(d, acc[6], b1.z); o[7] = fmaf(d, acc[7], b1.w);
#pragma unroll
        for (int j = 0; j < 8; ++j) o[j] = o[j] > 0.f ? o[j] : 0.f;
        uint4 w;
        w.x = (unsigned)f2bf(o[0]) | ((unsigned)f2bf(o[1]) << 16);
        w.y = (unsigned)f2bf(o[2]) | ((unsigned)f2bf(o[3]) << 16);
        w.z = (unsigned)f2bf(o[4]) | ((unsigned)f2bf(o[5]) << 16);
        w.w = (unsigned)f2bf(o[6]) | ((unsigned)f2bf(o[7]) << 16);
        *(uint4*)(z + ((size_t)node << 6) + (q << 3)) = w;
    }
}

// ---- gi via MFMA: gi[m][j] = (Zb2 @ wihT)[m][j] + bih[j] ----------------
__global__ __launch_bounds__(256) void giall_mfma_kernel(
        const unsigned short* __restrict__ Zb6, const unsigned short* __restrict__ Bfrag,
        const float* __restrict__ bih, unsigned short* __restrict__ gi) {
    int w = threadIdx.x >> 6, lane = threadIdx.x & 63;
    int tile = blockIdx.x * 4 + w;
    int m0 = tile << 4;
    int r16 = lane & 15, kg = lane >> 4;
    const unsigned short* zrow = Zb6 + ((size_t)(m0 + r16) << 6) + (kg << 3);
    bf16x8 a0 = *(const bf16x8*)zrow;
    bf16x8 a1 = *(const bf16x8*)(zrow + 32);
    f32x4 acc[12];
#pragma unroll
    for (int jt = 0; jt < 12; ++jt) {
        bf16x8 b0 = *(const bf16x8*)(Bfrag + ((size_t)((jt << 1) + 0) << 9) + (lane << 3));
        bf16x8 b1 = *(const bf16x8*)(Bfrag + ((size_t)((jt << 1) + 1) << 9) + (lane << 3));
        f32x4 c = {0.f, 0.f, 0.f, 0.f};
        c = __builtin_amdgcn_mfma_f32_16x16x32_bf16(a0, b0, c, 0, 0, 0);
        c = __builtin_amdgcn_mfma_f32_16x16x32_bf16(a1, b1, c, 0, 0, 0);
        acc[jt] = c;
    }
#pragma unroll
    for (int jt = 0; jt < 12; ++jt) {
        float bi = bih[jt * 16 + r16];
#pragma unroll
        for (int reg = 0; reg < 4; ++reg) {
            int node = m0 + (kg << 2) + reg;
            gi[(size_t)node * 192 + jt * 16 + r16] = f2bf(acc[jt][reg] + bi);
        }
    }
}

// ---- fused 6-step GRU v6: RBG=4 nodes/wave, 4 waves/block (5000 waves) --
__global__ __launch_bounds__(256) void gru6_kernel(
        const unsigned short* __restrict__ gi,
        const unsigned* __restrict__ Wh01, const unsigned short* __restrict__ Whn,
        const float* __restrict__ bhh, float* __restrict__ hfinal) {
    __shared__ unsigned sW01[HH * HH];        // 16 KB
    __shared__ unsigned short sWn[HH * HH];   // 8 KB
    __shared__ float hs[4][RBG][HH];          // 4 KB
    int tid = threadIdx.x;
    int wid = tid >> 6, lane = tid & 63;
    int nbase = (blockIdx.x * 4 + wid) * RBG;

    for (int i = tid; i < HH * HH; i += 256) { sW01[i] = Wh01[i]; sWn[i] = Whn[i]; }
    __syncthreads();

#pragma unroll
    for (int r = 0; r < RBG; ++r) hs[wid][r][lane] = 0.f;
    float bh0 = bhh[lane], bh1 = bhh[64 + lane], bh2 = bhh[128 + lane];

#pragma unroll 1
    for (int t = 0; t < TT; ++t) {
        float aR[RBG], aZ[RBG], aN[RBG];
#pragma unroll
        for (int r = 0; r < RBG; ++r) { aR[r] = aZ[r] = aN[r] = 0.f; }
#pragma unroll 1
        for (int k0 = 0; k0 < 16; ++k0) {
            float4 hv[RBG];
#pragma unroll
            for (int r = 0; r < RBG; ++r) hv[r] = *(const float4*)(&hs[wid][r][k0 << 2]);
#pragma unroll
            for (int u = 0; u < 4; ++u) {
                int k = k0 * 4 + u;
                unsigned w01 = sW01[(k << 6) + lane];
                float w_hr = bflo(w01), w_hz = bfhi(w01);
                float w_hn = bflo((unsigned)sWn[(k << 6) + lane]);
#pragma unroll
                for (int r = 0; r < RBG; ++r) {
                    float hk = (u == 0) ? hv[r].x : (u == 1) ? hv[r].y
                             : (u == 2) ? hv[r].z : hv[r].w;
                    aR[r] = fmaf(hk, w_hr, aR[r]);
                    aZ[r] = fmaf(hk, w_hz, aZ[r]);
                    aN[r] = fmaf(hk, w_hn, aN[r]);
                }
            }
        }
        const unsigned short* gp = gi + ((size_t)t * NN + nbase) * 192;
#pragma unroll
        for (int r = 0; r < RBG; ++r) {
            size_t gb = (size_t)r * 192;
            float gr = bflo((unsigned)gp[gb + lane]);
            float gz = bflo((unsigned)gp[gb + 64 + lane]);
            float gn = bflo((unsigned)gp[gb + 128 + lane]);
            float rr = fsig(gr + aR[r] + bh0);
            float zz = fsig(gz + aZ[r] + bh1);
            float nn_ = ftanh(gn + rr * (aN[r] + bh2));
            hs[wid][r][lane] = (1.f - zz) * nn_ + zz * hs[wid][r][lane];
        }
    }
#pragma unroll
    for (int r = 0; r < RBG; ++r)
        hfinal[((size_t)(nbase + r) << 6) + lane] = hs[wid][r][lane];
}

// ---- fused MLP head: out = sigmoid(relu(h@W3+b3)@W4 + b4) ---------------
__global__ void head_kernel(const float* __restrict__ h, const float* __restrict__ W3,
                            const float* __restrict__ b3, const float* __restrict__ W4,
                            const float* __restrict__ b4, float* __restrict__ out) {
    int nbase = blockIdx.x * RB;
    int lane = threadIdx.x;
    float acc[RB];
#pragma unroll
    for (int r = 0; r < RB; ++r) acc[r] = 0.f;
    for (int k0 = 0; k0 < 16; ++k0) {
        float4 hv[RB];
#pragma unroll
        for (int r = 0; r < RB; ++r)
            hv[r] = ((const float4*)(h + ((size_t)(nbase + r) << 6)))[k0];
#pragma unroll
        for (int u = 0; u < 4; ++u) {
            float w = W3[(k0 * 4 + u) * HH + lane];
#pragma unroll
            for (int r = 0; r < RB; ++r) {
                float hk = (u == 0) ? hv[r].x : (u == 1) ? hv[r].y : (u == 2) ? hv[r].z : hv[r].w;
                acc[r] = fmaf(hk, w, acc[r]);
            }
        }
    }
    float bb = b3[lane], w4 = W4[lane], b40 = b4[0];
#pragma unroll
    for (int r = 0; r < RB; ++r) {
        float v = acc[r] + bb;
        v = v > 0.f ? v : 0.f;
        float s = v * w4;
        s += __shfl_xor(s, 32); s += __shfl_xor(s, 16); s += __shfl_xor(s, 8);
        s += __shfl_xor(s, 4);  s += __shfl_xor(s, 2);  s += __shfl_xor(s, 1);
        if (lane == r) out[nbase + r] = 1.f / (1.f + expf(-(s + b40)));
    }
}

extern "C" void kernel_launch(void* const* d_in, const int* in_sizes, int n_in,
                              void* d_out, int out_size, void* d_ws, size_t ws_size,
                              hipStream_t stream) {
    const float* nf    = (const float*)d_in[0];
    const int*   edges = (const int*)  d_in[1];
    const float* W1  = (const float*)d_in[2];
    const float* b1  = (const float*)d_in[3];
    const float* W2  = (const float*)d_in[4];
    const float* b2  = (const float*)d_in[5];
    const float* wih = (const float*)d_in[6];
    const float* whh = (const float*)d_in[7];
    const float* bih = (const float*)d_in[8];
    const float* bhh = (const float*)d_in[9];
    const float* W3  = (const float*)d_in[10];
    const float* b3  = (const float*)d_in[11];
    const float* W4  = (const float*)d_in[12];
    const float* b4  = (const float*)d_in[13];
    float* out = (float*)d_out;

    // workspace layout
    int* wsi      = (int*)d_ws;
    int* gcur     = wsi;                              // 6*NBKT (zeroed)
    int* gbase    = gcur + 6 * NBKT;                  // 6*NBKT
    int* rowptr6  = gbase + 6 * NBKT;                 // 6*(NN+1)
    int* col6     = rowptr6 + 6 * (NN + 1);           // 6*EE
    int* bucketArr= col6 + (size_t)6 * EE;            // 6*NBKT*CAP
    uintptr_t fbase = ((uintptr_t)(bucketArr + (size_t)6 * NBKT * CAP) + 15) & ~(uintptr_t)15;
    unsigned short* Bfrag = (unsigned short*)fbase;   // 24*64*8 bf16
    unsigned short* Bfrag2= Bfrag + 24 * 64 * 8;      // 8*64*8 bf16
    unsigned* Wh01= (unsigned*)(Bfrag2 + 8 * 64 * 8); // 4096 uint
    unsigned short* Whn = (unsigned short*)(Wh01 + HH * HH);  // 4096 ushort
    float* dinv6 = (float*)(Whn + HH * HH);           // 6*NN
    float* Hf    = dinv6 + 6 * NN;                    // NN*HH (final h, fp32)
    unsigned short* Yb    = (unsigned short*)(Hf + (size_t)NN * HH);  // 6*NN*HH bf16
    unsigned short* Y2all = Yb + (size_t)6 * NN * HH;                 // 6*NN*HH bf16
    unsigned short* Zb1   = Y2all + (size_t)6 * NN * HH;              // 6*NN*HH bf16
    unsigned short* Zb2   = Zb1 + (size_t)6 * NN * HH;                // 6*NN*HH bf16
    unsigned short* gi    = Zb2 + (size_t)6 * NN * HH;                // 6*NN*192 bf16

    const int BS  = 256;
    const int gNH = (NN * HH + BS - 1) / BS;   // 5000
    const int gRB = NN / RB;                   // 2500
    const int gG6 = NN / (RBG * 4);            // 1250 blocks x 4 waves
    const int gMM = (TT * NN) / 64;            // 1875
    const int gBIN = (EE + EPB - 1) / EPB;     // 157

    hipMemsetAsync(gcur, 0, 6 * NBKT * sizeof(int), stream);
    pack_gruh_kernel<<<(HH * HH + BS - 1) / BS, BS, 0, stream>>>(whh, Wh01, Whn);
    pack_bfrag_kernel<<<(24 * 64 * 8 + BS - 1) / BS, BS, 0, stream>>>(wih, Bfrag);
    pack_bfrag2_kernel<<<(8 * 64 * 8 + BS - 1) / BS, BS, 0, stream>>>(W2, Bfrag2);

    bin6_kernel<<<dim3(gBIN, TT), BS, 0, stream>>>(edges, gcur, bucketArr);
    scan_gcur_kernel<<<TT, BS, 0, stream>>>(gcur, gbase, rowptr6);
    regroup6_kernel<<<dim3(NBKT, TT), BS, 0, stream>>>(gcur, gbase, bucketArr,
                                                       rowptr6, dinv6, col6);
    y1all_kernel<<<dim3(gNH, TT), BS, 0, stream>>>(nf, W1, dinv6, Yb);

    // GCN layer 1 (all t) -> dense via MFMA (all t) -> GCN layer 2 (all t)
    gather6_kernel<<<dim3(gNH, TT), BS, 0, stream>>>(rowptr6, col6, dinv6, Yb, b1, Zb1);
    y2all_mfma_kernel<<<gMM, 256, 0, stream>>>(Zb1, Bfrag2, dinv6, Y2all);
    gather6_kernel<<<dim3(gNH, TT), BS, 0, stream>>>(rowptr6, col6, dinv6, Y2all, b2, Zb2);

    // gi = Zb2 @ wihT + bih via MFMA, then sequential h-only GRU
    giall_mfma_kernel<<<gMM, 256, 0, stream>>>(Zb2, Bfrag, bih, gi);
    gru6_kernel<<<gG6, 256, 0, stream>>>(gi, Wh01, Whn, bhh, Hf);

    head_kernel<<<gRB, 64, 0, stream>>>(Hf, W3, b3, W4, b4, out);
}